// Round 1
// baseline (5712.065 us; speedup 1.0000x reference)
//
#include <hip/hip_runtime.h>
#include <cmath>

// Problem constants
#define BATCH 16
#define SEQ 512
#define DMODEL 512
#define NDEPTH 4
#define NHEADS 8
#define DHEAD 64
#define DFF 2048
#define CBD 64
#define CBS 8192
#define MROWS (BATCH * SEQ) // 8192

// ---------------------------------------------------------------- zero output
__global__ void zero_kernel(float* __restrict__ p, int n) {
    int i = blockIdx.x * 256 + threadIdx.x;
    if (i < n) p[i] = 0.0f;
}

// ------------------------------------------------------------- codebook norms
__global__ void cbn_kernel(const float* __restrict__ cb, float* __restrict__ cbn) {
    int c = blockIdx.x * 256 + threadIdx.x;
    if (c >= CBS) return;
    const float* row = cb + (size_t)c * CBD;
    float s = 0.0f;
#pragma unroll
    for (int d = 0; d < CBD; ++d) s += row[d] * row[d];
    cbn[c] = s;
}

// ------------------------------------------------------------------ layernorm
// one wave per row of 512; block = 4 waves
__global__ __launch_bounds__(256) void ln_kernel(
    const float* __restrict__ X, float* __restrict__ Y,
    const float* __restrict__ g, const float* __restrict__ b) {
    int row  = blockIdx.x * 4 + (threadIdx.x >> 6);
    int lane = threadIdx.x & 63;
    const float* x = X + (size_t)row * DMODEL;
    float v[8];
    float s = 0.0f;
#pragma unroll
    for (int j = 0; j < 8; ++j) { v[j] = x[lane + j * 64]; s += v[j]; }
#pragma unroll
    for (int off = 32; off; off >>= 1) s += __shfl_xor(s, off);
    float mu  = s * (1.0f / DMODEL);
    float var = 0.0f;
#pragma unroll
    for (int j = 0; j < 8; ++j) { float d = v[j] - mu; var += d * d; }
#pragma unroll
    for (int off = 32; off; off >>= 1) var += __shfl_xor(var, off);
    float r = rsqrtf(var * (1.0f / DMODEL) + 1e-5f);
    float* y = Y + (size_t)row * DMODEL;
#pragma unroll
    for (int j = 0; j < 8; ++j) {
        int d = lane + j * 64;
        y[d] = (v[j] - mu) * r * g[d] + b[d];
    }
}

// ----------------------------------------------------------------------- gemm
// C[M,N] = epi(A[M,K] @ B[K,N]); epi: +bias[n], +pos[(m%512)*N+n], +res[m,n], gelu
// 64x64 tile, K-step 16, 256 threads, 4x4 micro-tile per thread. fp32 baseline.
__global__ __launch_bounds__(256) void gemm_kernel(
    const float* __restrict__ A, const float* __restrict__ Bm,
    float* __restrict__ C, const float* __restrict__ bias,
    const float* __restrict__ res, const float* __restrict__ pos,
    int M, int N, int K, int gelu) {
    __shared__ float As[16][68]; // [k][m], padded (+4 keeps float4 alignment, breaks 64-stride)
    __shared__ float Bs[16][64]; // [k][n]

    int tid = threadIdx.x;
    int tx = tid & 15, ty = tid >> 4;
    // loader mapping
    int a_m = tid >> 2;        // 0..63
    int a_k = (tid & 3) * 4;   // 0,4,8,12
    int b_k = tid >> 4;        // 0..15
    int b_n = (tid & 15) * 4;  // 0..60

    const float* Arow  = A + (size_t)(blockIdx.x * 64 + a_m) * K;
    const float* Bcol  = Bm + (size_t)blockIdx.y * 64 + b_n;

    float acc[4][4] = {};

    for (int k0 = 0; k0 < K; k0 += 16) {
        float4 av = *(const float4*)(Arow + k0 + a_k);
        float4 bv = *(const float4*)(Bcol + (size_t)(k0 + b_k) * N);
        __syncthreads(); // previous iteration's compute done before overwrite
        As[a_k + 0][a_m] = av.x;
        As[a_k + 1][a_m] = av.y;
        As[a_k + 2][a_m] = av.z;
        As[a_k + 3][a_m] = av.w;
        *(float4*)(&Bs[b_k][b_n]) = bv;
        __syncthreads();
#pragma unroll
        for (int kk = 0; kk < 16; ++kk) {
            float4 a4 = *(const float4*)(&As[kk][ty * 4]);
            float4 b4 = *(const float4*)(&Bs[kk][tx * 4]);
            float ar[4] = {a4.x, a4.y, a4.z, a4.w};
            float br[4] = {b4.x, b4.y, b4.z, b4.w};
#pragma unroll
            for (int i = 0; i < 4; ++i)
#pragma unroll
                for (int j = 0; j < 4; ++j) acc[i][j] = fmaf(ar[i], br[j], acc[i][j]);
        }
    }

    int m0 = blockIdx.x * 64 + ty * 4;
    int n0 = blockIdx.y * 64 + tx * 4;
#pragma unroll
    for (int i = 0; i < 4; ++i) {
        int m = m0 + i;
        float vv[4];
#pragma unroll
        for (int j = 0; j < 4; ++j) {
            float t = acc[i][j];
            int n = n0 + j;
            if (bias) t += bias[n];
            if (pos) t += pos[(size_t)(m & (SEQ - 1)) * N + n];
            if (res) t += res[(size_t)m * N + n];
            if (gelu) {
                float u = t;
                t = 0.5f * u * (1.0f + tanhf(0.7978845608028654f * (u + 0.044715f * u * u * u)));
            }
            vv[j] = t;
        }
        *(float4*)(C + (size_t)m * N + n0) = make_float4(vv[0], vv[1], vv[2], vv[3]);
    }
}

// ------------------------------------------------------------ fused attention
// one block per (b, head, 16-query tile). scores for full S=512 kept in LDS.
__global__ __launch_bounds__(256) void attn_kernel(
    const float* __restrict__ Q, const float* __restrict__ K,
    const float* __restrict__ V, float* __restrict__ O) {
    int qt = blockIdx.x & 31;
    int hh = (blockIdx.x >> 5) & 7;
    int bb = blockIdx.x >> 8;

    __shared__ float qs[16][64];
    __shared__ float sc[16][512];
    __shared__ float kv[64][65]; // pad 65: breaks 64-stride bank aliasing

    int tid = threadIdx.x;
    // load q tile (16 rows x 64)
    {
        int r = tid >> 4, c = (tid & 15) * 4;
        const float* src = Q + ((size_t)(bb * SEQ + qt * 16 + r) * DMODEL) + hh * 64 + c;
        *(float4*)(&qs[r][c]) = *(const float4*)src;
    }

    const float scale = 0.125f; // 64^-0.5
    for (int kt = 0; kt < 8; ++kt) {
        __syncthreads();
#pragma unroll
        for (int j = 0; j < 4; ++j) {
            int idx = tid + j * 256; // float4 units, 0..1023
            int r = idx >> 4, c = (idx & 15) * 4;
            const float* src = K + ((size_t)(bb * SEQ + kt * 64 + r) * DMODEL) + hh * 64 + c;
            float4 v4 = *(const float4*)src;
            kv[r][c] = v4.x; kv[r][c + 1] = v4.y; kv[r][c + 2] = v4.z; kv[r][c + 3] = v4.w;
        }
        __syncthreads();
        int kk = tid & 63;
#pragma unroll
        for (int j = 0; j < 4; ++j) {
            int qi = (tid >> 6) + j * 4;
            float s = 0.0f;
#pragma unroll
            for (int d = 0; d < 64; ++d) s = fmaf(qs[qi][d], kv[kk][d], s);
            sc[qi][kt * 64 + kk] = s * scale;
        }
    }
    __syncthreads();

    // softmax: wave w owns rows {w, w+4, w+8, w+12}
    int lane = tid & 63;
    int w = tid >> 6;
    for (int rr = 0; rr < 4; ++rr) {
        int qi = w + rr * 4;
        float m = -1e30f;
#pragma unroll
        for (int j = 0; j < 8; ++j) m = fmaxf(m, sc[qi][lane + j * 64]);
#pragma unroll
        for (int off = 32; off; off >>= 1) m = fmaxf(m, __shfl_xor(m, off));
        float e[8];
        float sum = 0.0f;
#pragma unroll
        for (int j = 0; j < 8; ++j) { e[j] = __expf(sc[qi][lane + j * 64] - m); sum += e[j]; }
#pragma unroll
        for (int off = 32; off; off >>= 1) sum += __shfl_xor(sum, off);
        float inv = 1.0f / sum;
#pragma unroll
        for (int j = 0; j < 8; ++j) sc[qi][lane + j * 64] = e[j] * inv;
    }

    // AV: thread owns (rows {w+4j}, col d = lane)
    float acc[4] = {0.f, 0.f, 0.f, 0.f};
    int d = lane;
    for (int vt = 0; vt < 8; ++vt) {
        __syncthreads();
#pragma unroll
        for (int j = 0; j < 4; ++j) {
            int idx = tid + j * 256;
            int r = idx >> 4, c = (idx & 15) * 4;
            const float* src = V + ((size_t)(bb * SEQ + vt * 64 + r) * DMODEL) + hh * 64 + c;
            float4 v4 = *(const float4*)src;
            kv[r][c] = v4.x; kv[r][c + 1] = v4.y; kv[r][c + 2] = v4.z; kv[r][c + 3] = v4.w;
        }
        __syncthreads();
#pragma unroll
        for (int j = 0; j < 4; ++j) {
            int qi = w + j * 4;
            float a = 0.0f;
#pragma unroll
            for (int k2 = 0; k2 < 64; ++k2) a = fmaf(sc[qi][vt * 64 + k2], kv[k2][d], a);
            acc[j] += a;
        }
    }
#pragma unroll
    for (int j = 0; j < 4; ++j) {
        int qi = w + j * 4;
        O[((size_t)(bb * SEQ + qt * 16 + qi) * DMODEL) + hh * 64 + d] = acc[j];
    }
}

// ------------------------------------------------------------------------- VQ
// one block per 16 (b,s) rows (all same b). Codebook streamed through LDS.
__global__ __launch_bounds__(256) void vq_kernel(
    const float* __restrict__ Z, const float* __restrict__ CB,
    const float* __restrict__ CBN, float* __restrict__ out) {
    __shared__ float zs[16][64];
    __shared__ float cbt[64][65];
    __shared__ float rbest[16][16];
    __shared__ int ribest[16][16];
    __shared__ float psum[4][64];
    __shared__ float cl4[4];

    int tid = threadIdx.x;
    int row0 = blockIdx.x * 16;
    {
        int r = tid >> 4, c = (tid & 15) * 4;
        *(float4*)(&zs[r][c]) = *(const float4*)(Z + (size_t)(row0 + r) * CBD + c);
    }
    int r = tid >> 4;   // row this thread scores for
    int cl = tid & 15;  // code sub-lane
    float best = 3.4e38f;
    int bidx = 0;

    for (int ct = 0; ct < CBS / 64; ++ct) {
        __syncthreads();
#pragma unroll
        for (int j = 0; j < 4; ++j) {
            int idx = tid + j * 256;
            int cr = idx >> 4, cc = (idx & 15) * 4;
            float4 v4 = *(const float4*)(CB + (size_t)(ct * 64 + cr) * CBD + cc);
            cbt[cr][cc] = v4.x; cbt[cr][cc + 1] = v4.y; cbt[cr][cc + 2] = v4.z; cbt[cr][cc + 3] = v4.w;
        }
        __syncthreads();
#pragma unroll
        for (int j = 0; j < 4; ++j) {
            int c = cl + j * 16;
            float dot = 0.0f;
#pragma unroll
            for (int d = 0; d < 64; ++d) dot = fmaf(zs[r][d], cbt[c][d], dot);
            int gc = ct * 64 + c;
            float score = CBN[gc] - 2.0f * dot; // |z|^2 constant per row, drop it
            if (score < best || (score == best && gc < bidx)) { best = score; bidx = gc; }
        }
    }
    rbest[r][cl] = best;
    ribest[r][cl] = bidx;
    __syncthreads();
    if (tid < 16) {
        float bb = rbest[tid][0];
        int bi = ribest[tid][0];
        for (int t = 1; t < 16; ++t) {
            float s = rbest[tid][t];
            int i2 = ribest[tid][t];
            if (s < bb || (s == bb && i2 < bi)) { bb = s; bi = i2; }
        }
        ribest[tid][0] = bi;
    }
    __syncthreads();

    // accumulate sum_s codebook[idx] (per b) and commit loss
    int w = tid >> 6, d = tid & 63;
    float qacc = 0.0f, closs = 0.0f;
#pragma unroll
    for (int j = 0; j < 4; ++j) {
        int r2 = w + 4 * j;
        int bi = ribest[r2][0];
        float q = CB[(size_t)bi * CBD + d];
        qacc += q;
        float diff = q - zs[r2][d];
        closs += diff * diff;
    }
    psum[w][d] = qacc;
#pragma unroll
    for (int off = 32; off; off >>= 1) closs += __shfl_xor(closs, off);
    if (d == 0) cl4[w] = closs;
    __syncthreads();
    if (tid < 64) {
        float t = psum[0][tid] + psum[1][tid] + psum[2][tid] + psum[3][tid];
        int b = row0 >> 9; // 512 rows per batch
        atomicAdd(out + b * 64 + tid, t);
    }
    if (tid == 0)
        atomicAdd(out + 1024, (cl4[0] + cl4[1] + cl4[2] + cl4[3]) * (1.0f / (float)(MROWS * CBD)));
}

// -------------------------------------------------------------------- launch
extern "C" void kernel_launch(void* const* d_in, const int* in_sizes, int n_in,
                              void* d_out, int out_size, void* d_ws, size_t ws_size,
                              hipStream_t stream) {
    const float* x    = (const float*)d_in[0];
    const float* w_in = (const float*)d_in[1];
    const float* b_in = (const float*)d_in[2];
    const float* pos  = (const float*)d_in[3];
    const float* ln1g = (const float*)d_in[4];
    const float* ln1b = (const float*)d_in[5];
    const float* wq   = (const float*)d_in[6];
    const float* wk   = (const float*)d_in[7];
    const float* wv   = (const float*)d_in[8];
    const float* wo   = (const float*)d_in[9];
    const float* ln2g = (const float*)d_in[10];
    const float* ln2b = (const float*)d_in[11];
    const float* ffw1 = (const float*)d_in[12];
    const float* ffb1 = (const float*)d_in[13];
    const float* ffw2 = (const float*)d_in[14];
    const float* ffb2 = (const float*)d_in[15];
    const float* lnfg = (const float*)d_in[16];
    const float* lnfb = (const float*)d_in[17];
    const float* wout = (const float*)d_in[18];
    const float* bout = (const float*)d_in[19];
    const float* cb   = (const float*)d_in[20];
    float* out = (float*)d_out;

    // workspace layout (floats):
    //   h     [8192*512]
    //   t0    [8192*512]
    //   big   [8192*2048]  = q|k|v|o during attention, ffmid during FF
    //   zb    [8192*64]
    //   cbn   [8192]
    float* ws = (float*)d_ws;
    float* h  = ws;
    float* t0 = h + (size_t)MROWS * DMODEL;
    float* big = t0 + (size_t)MROWS * DMODEL;
    float* qb = big;
    float* kb = big + (size_t)MROWS * DMODEL;
    float* vb = big + 2 * (size_t)MROWS * DMODEL;
    float* ob = big + 3 * (size_t)MROWS * DMODEL;
    float* ffmid = big;
    float* zb  = big + (size_t)MROWS * DFF;
    float* cbn = zb + (size_t)MROWS * CBD;

    dim3 blk(256);

    zero_kernel<<<dim3((out_size + 255) / 256), blk, 0, stream>>>(out, out_size);
    cbn_kernel<<<dim3(CBS / 256), blk, 0, stream>>>(cb, cbn);

    // input projection + pos emb
    gemm_kernel<<<dim3(MROWS / 64, DMODEL / 64), blk, 0, stream>>>(
        x, w_in, h, b_in, nullptr, pos, MROWS, DMODEL, DMODEL, 0);

    for (int l = 0; l < NDEPTH; ++l) {
        const float* wq_l = wq + (size_t)l * DMODEL * DMODEL;
        const float* wk_l = wk + (size_t)l * DMODEL * DMODEL;
        const float* wv_l = wv + (size_t)l * DMODEL * DMODEL;
        const float* wo_l = wo + (size_t)l * DMODEL * DMODEL;

        ln_kernel<<<dim3(MROWS / 4), blk, 0, stream>>>(h, t0, ln1g + l * DMODEL, ln1b + l * DMODEL);
        gemm_kernel<<<dim3(MROWS / 64, DMODEL / 64), blk, 0, stream>>>(
            t0, wq_l, qb, nullptr, nullptr, nullptr, MROWS, DMODEL, DMODEL, 0);
        gemm_kernel<<<dim3(MROWS / 64, DMODEL / 64), blk, 0, stream>>>(
            t0, wk_l, kb, nullptr, nullptr, nullptr, MROWS, DMODEL, DMODEL, 0);
        gemm_kernel<<<dim3(MROWS / 64, DMODEL / 64), blk, 0, stream>>>(
            t0, wv_l, vb, nullptr, nullptr, nullptr, MROWS, DMODEL, DMODEL, 0);
        attn_kernel<<<dim3(BATCH * NHEADS * (SEQ / 16)), blk, 0, stream>>>(qb, kb, vb, ob);
        gemm_kernel<<<dim3(MROWS / 64, DMODEL / 64), blk, 0, stream>>>(
            ob, wo_l, h, nullptr, h, nullptr, MROWS, DMODEL, DMODEL, 0);

        ln_kernel<<<dim3(MROWS / 4), blk, 0, stream>>>(h, t0, ln2g + l * DMODEL, ln2b + l * DMODEL);
        gemm_kernel<<<dim3(MROWS / 64, DFF / 64), blk, 0, stream>>>(
            t0, ffw1 + (size_t)l * DMODEL * DFF, ffmid, ffb1 + l * DFF, nullptr, nullptr,
            MROWS, DFF, DMODEL, 1);
        gemm_kernel<<<dim3(MROWS / 64, DMODEL / 64), blk, 0, stream>>>(
            ffmid, ffw2 + (size_t)l * DFF * DMODEL, h, ffb2 + l * DMODEL, h, nullptr,
            MROWS, DMODEL, DFF, 0);
    }

    ln_kernel<<<dim3(MROWS / 4), blk, 0, stream>>>(h, t0, lnfg, lnfb);
    gemm_kernel<<<dim3(MROWS / 64, CBD / 64), blk, 0, stream>>>(
        t0, wout, zb, bout, nullptr, nullptr, MROWS, CBD, DMODEL, 0);
    vq_kernel<<<dim3(MROWS / 16), blk, 0, stream>>>(zb, cb, cbn, out);
}

// Round 2
// 3962.919 us; speedup vs baseline: 1.4414x; 1.4414x over previous
//
#include <hip/hip_runtime.h>
#include <cmath>

#define BATCH 16
#define SEQ 512
#define DMODEL 512
#define NDEPTH 4
#define NHEADS 8
#define DHEAD 64
#define DFF 2048
#define CBD 64
#define CBS 8192
#define MROWS (BATCH * SEQ) // 8192

typedef unsigned short u16;
typedef __attribute__((ext_vector_type(8))) short short8; // 8 bf16 = 4 VGPRs (MFMA A/B frag)
typedef __attribute__((ext_vector_type(4))) float f32x4;  // MFMA C/D frag

// ---------------------------------------------------------------- bf16 helpers
__device__ __forceinline__ u16 f2bf(float f) {
    unsigned u = __float_as_uint(f);
    u += 0x7fff + ((u >> 16) & 1); // RNE
    return (u16)(u >> 16);
}
__device__ __forceinline__ float bf2f(u16 h) {
    return __uint_as_float(((unsigned)h) << 16);
}

// async global->LDS 16B: LDS dest must be wave-uniform base + lane*16
__device__ __forceinline__ void async16(u16* lds, const u16* g) {
    __builtin_amdgcn_global_load_lds(
        (const __attribute__((address_space(1))) unsigned int*)g,
        (__attribute__((address_space(3))) unsigned int*)lds, 16, 0, 0);
}

__device__ __forceinline__ float gelu_tanh(float u) {
    return 0.5f * u * (1.0f + tanhf(0.7978845608028654f * (u + 0.044715f * u * u * u)));
}

// ---------------------------------------------------------------- zero output
__global__ void zero_kernel(float* __restrict__ p, int n) {
    int i = blockIdx.x * 256 + threadIdx.x;
    if (i < n) p[i] = 0.0f;
}

// ------------------------------------------------------------- codebook norms
__global__ void cbn_kernel(const float* __restrict__ cb, float* __restrict__ cbn) {
    int c = blockIdx.x * 256 + threadIdx.x;
    if (c >= CBS) return;
    const float* row = cb + (size_t)c * CBD;
    float s = 0.0f;
#pragma unroll
    for (int d = 0; d < CBD; ++d) s += row[d] * row[d];
    cbn[c] = s;
}

// ------------------------------------------- fp32 transpose (codebook -> cbT)
// W [K][N] -> T [N][K]
__global__ __launch_bounds__(256) void ftrans_kernel(
    const float* __restrict__ W, float* __restrict__ T, int K, int N) {
    __shared__ float t[32][33];
    int n0 = blockIdx.x * 32, k0 = blockIdx.y * 32;
    int tx = threadIdx.x & 31, ty = threadIdx.x >> 5;
#pragma unroll
    for (int r = ty; r < 32; r += 8) t[r][tx] = W[(size_t)(k0 + r) * N + n0 + tx];
    __syncthreads();
#pragma unroll
    for (int r = ty; r < 32; r += 8) T[(size_t)(n0 + r) * K + k0 + tx] = t[tx][r];
}

// ------------------------- weight transpose + split: W [z][K][N] -> T [z][N][K]
__global__ __launch_bounds__(256) void wtrans_kernel(
    const float* __restrict__ W, u16* __restrict__ Th, u16* __restrict__ Tl,
    int K, int N, long inLS, long outLS) {
    __shared__ float t[32][33];
    const float* Ws = W + (size_t)blockIdx.z * inLS;
    u16* Tho = Th + (size_t)blockIdx.z * outLS;
    u16* Tlo = Tl + (size_t)blockIdx.z * outLS;
    int n0 = blockIdx.x * 32, k0 = blockIdx.y * 32;
    int tx = threadIdx.x & 31, ty = threadIdx.x >> 5;
#pragma unroll
    for (int r = ty; r < 32; r += 8) t[r][tx] = Ws[(size_t)(k0 + r) * N + n0 + tx];
    __syncthreads();
#pragma unroll
    for (int r = ty; r < 32; r += 8) {
        float v = t[tx][r];
        size_t o = (size_t)(n0 + r) * K + k0 + tx;
        u16 hh = f2bf(v);
        Tho[o] = hh;
        Tlo[o] = f2bf(v - bf2f(hh));
    }
}

// ------------------------------------------------ elementwise fp32 -> (hi,lo)
__global__ void split_kernel(const float* __restrict__ X, u16* __restrict__ H,
                             u16* __restrict__ L, int n) {
    int i = blockIdx.x * 256 + threadIdx.x;
    if (i < n) {
        float v = X[i];
        u16 hh = f2bf(v);
        H[i] = hh;
        L[i] = f2bf(v - bf2f(hh));
    }
}

// ------------------------------------------------------------------ layernorm
// one wave per row of 512; block = 4 waves. Writes fp32 + optional split planes.
__global__ __launch_bounds__(256) void ln_kernel(
    const float* __restrict__ X, float* __restrict__ Y,
    u16* __restrict__ Yh, u16* __restrict__ Yl,
    const float* __restrict__ g, const float* __restrict__ b) {
    int row  = blockIdx.x * 4 + (threadIdx.x >> 6);
    int lane = threadIdx.x & 63;
    const float* x = X + (size_t)row * DMODEL;
    float v[8];
    float s = 0.0f;
#pragma unroll
    for (int j = 0; j < 8; ++j) { v[j] = x[lane + j * 64]; s += v[j]; }
#pragma unroll
    for (int off = 32; off; off >>= 1) s += __shfl_xor(s, off);
    float mu  = s * (1.0f / DMODEL);
    float var = 0.0f;
#pragma unroll
    for (int j = 0; j < 8; ++j) { float d = v[j] - mu; var += d * d; }
#pragma unroll
    for (int off = 32; off; off >>= 1) var += __shfl_xor(var, off);
    float r = rsqrtf(var * (1.0f / DMODEL) + 1e-5f);
#pragma unroll
    for (int j = 0; j < 8; ++j) {
        int d = lane + j * 64;
        float y = (v[j] - mu) * r * g[d] + b[d];
        size_t o = (size_t)row * DMODEL + d;
        Y[o] = y;
        if (Yh) {
            u16 hh = f2bf(y);
            Yh[o] = hh;
            Yl[o] = f2bf(y - bf2f(hh));
        }
    }
}

// --------------------------------------------------------- bf16x3 MFMA GEMM
// C = epi(A @ B), fp32-accurate via hi/lo bf16 split:
//   A@B ~= Ah@Bh + Al@Bh + Ah@Bl   (3 passes over K, plane-switched)
// A planes [M][K] bf16, B planes [N][K] bf16 (pre-transposed).
// 128x128 tile, BK=32, 256 threads = 4 waves in 2x2, each wave 64x64 (4x4 MFMA frags).
__global__ __launch_bounds__(256) void gemm3_kernel(
    const u16* __restrict__ Ah, const u16* __restrict__ Al,
    const u16* __restrict__ Bh, const u16* __restrict__ Bl,
    float* __restrict__ Cf, u16* __restrict__ Ch, u16* __restrict__ Cl,
    const float* __restrict__ bias, const float* __restrict__ res,
    const float* __restrict__ pos, int M, int N, int K, int gelu) {
    __shared__ __align__(16) u16 AsU[128 * 32];
    __shared__ __align__(16) u16 BsU[128 * 32];

    int tid  = threadIdx.x;
    int w    = tid >> 6, lane = tid & 63;
    int wr   = w >> 1, wc = w & 1;
    int quad = lane >> 4, l16 = lane & 15;
    int m0   = blockIdx.x * 128;
    int n0   = blockIdx.y * 128;

    f32x4 acc[4][4];
#pragma unroll
    for (int i = 0; i < 4; ++i)
#pragma unroll
        for (int j = 0; j < 4; ++j) acc[i][j] = (f32x4){0.f, 0.f, 0.f, 0.f};

    // staging indices: thread covers 16B chunks at (it*4096 + tid*16) bytes of the 8KB tile
    int off0 = tid * 16;
    int row0s = off0 >> 6, ke0 = (off0 & 63) >> 1;
    int off1 = 4096 + tid * 16;
    int row1s = off1 >> 6, ke1 = (off1 & 63) >> 1;

#pragma unroll
    for (int pass = 0; pass < 3; ++pass) {
        const u16* Ap = (pass == 1) ? Al : Ah;
        const u16* Bp = (pass == 2) ? Bl : Bh;
        const u16* Abase = Ap + (size_t)m0 * K;
        const u16* Bbase = Bp + (size_t)n0 * K;
        for (int ks = 0; ks < K; ks += 32) {
            __syncthreads(); // previous chunk consumed
            async16(&AsU[off0 >> 1], Abase + (size_t)row0s * K + ks + ke0);
            async16(&BsU[off0 >> 1], Bbase + (size_t)row0s * K + ks + ke0);
            async16(&AsU[off1 >> 1], Abase + (size_t)row1s * K + ks + ke1);
            async16(&BsU[off1 >> 1], Bbase + (size_t)row1s * K + ks + ke1);
            __syncthreads(); // drains vmcnt before barrier
            short8 af[4], bf[4];
#pragma unroll
            for (int i = 0; i < 4; ++i)
                af[i] = *(const short8*)&AsU[(wr * 64 + i * 16 + l16) * 32 + quad * 8];
#pragma unroll
            for (int i = 0; i < 4; ++i)
                bf[i] = *(const short8*)&BsU[(wc * 64 + i * 16 + l16) * 32 + quad * 8];
#pragma unroll
            for (int i = 0; i < 4; ++i)
#pragma unroll
                for (int j = 0; j < 4; ++j)
                    acc[i][j] = __builtin_amdgcn_mfma_f32_16x16x32_bf16(af[i], bf[j], acc[i][j], 0, 0, 0);
        }
    }

    // epilogue: C/D layout col=lane&15, row=quad*4+reg
    int mbase = m0 + wr * 64;
    int nbase = n0 + wc * 64;
#pragma unroll
    for (int mi = 0; mi < 4; ++mi)
#pragma unroll
        for (int ni = 0; ni < 4; ++ni) {
            f32x4 a = acc[mi][ni];
#pragma unroll
            for (int r = 0; r < 4; ++r) {
                int m = mbase + mi * 16 + quad * 4 + r;
                int n = nbase + ni * 16 + l16;
                float v = a[r];
                if (bias) v += bias[n];
                if (pos)  v += pos[(size_t)(m & (SEQ - 1)) * N + n];
                if (res)  v += res[(size_t)m * N + n];
                if (gelu) v = gelu_tanh(v);
                size_t o = (size_t)m * N + n;
                if (Cf) Cf[o] = v;
                if (Ch) {
                    u16 hh = f2bf(v);
                    Ch[o] = hh;
                    Cl[o] = f2bf(v - bf2f(hh));
                }
            }
        }
}

// ------------------------------------------------------------ fp32 GEMM (small)
// kept for the final out-projection (N=64): full fp32 precision into VQ.
__global__ __launch_bounds__(256) void gemm_kernel(
    const float* __restrict__ A, const float* __restrict__ Bm,
    float* __restrict__ C, const float* __restrict__ bias,
    int M, int N, int K) {
    __shared__ float As[16][68];
    __shared__ float Bs[16][64];
    int tid = threadIdx.x;
    int tx = tid & 15, ty = tid >> 4;
    int a_m = tid >> 2, a_k = (tid & 3) * 4;
    int b_k = tid >> 4, b_n = (tid & 15) * 4;
    const float* Arow = A + (size_t)(blockIdx.x * 64 + a_m) * K;
    const float* Bcol = Bm + (size_t)blockIdx.y * 64 + b_n;
    float acc[4][4] = {};
    for (int k0 = 0; k0 < K; k0 += 16) {
        float4 av = *(const float4*)(Arow + k0 + a_k);
        float4 bv = *(const float4*)(Bcol + (size_t)(k0 + b_k) * N);
        __syncthreads();
        As[a_k + 0][a_m] = av.x; As[a_k + 1][a_m] = av.y;
        As[a_k + 2][a_m] = av.z; As[a_k + 3][a_m] = av.w;
        *(float4*)(&Bs[b_k][b_n]) = bv;
        __syncthreads();
#pragma unroll
        for (int kk = 0; kk < 16; ++kk) {
            float4 a4 = *(const float4*)(&As[kk][ty * 4]);
            float4 b4 = *(const float4*)(&Bs[kk][tx * 4]);
            float ar[4] = {a4.x, a4.y, a4.z, a4.w};
            float br[4] = {b4.x, b4.y, b4.z, b4.w};
#pragma unroll
            for (int i = 0; i < 4; ++i)
#pragma unroll
                for (int j = 0; j < 4; ++j) acc[i][j] = fmaf(ar[i], br[j], acc[i][j]);
        }
    }
    int m0 = blockIdx.x * 64 + ty * 4;
    int n0 = blockIdx.y * 64 + tx * 4;
#pragma unroll
    for (int i = 0; i < 4; ++i) {
        float vv[4];
#pragma unroll
        for (int j = 0; j < 4; ++j) {
            float t = acc[i][j];
            if (bias) t += bias[n0 + j];
            vv[j] = t;
        }
        *(float4*)(C + (size_t)(m0 + i) * N + n0) = make_float4(vv[0], vv[1], vv[2], vv[3]);
    }
}

// ------------------------------------------------------------ fused attention
// one block per (b, head, 16-query tile). QKV packed [M][1536]. Output split bf16.
__global__ __launch_bounds__(256) void attn_kernel(
    const float* __restrict__ QKV, u16* __restrict__ Oh, u16* __restrict__ Ol) {
    int qt = blockIdx.x & 31;
    int hh = (blockIdx.x >> 5) & 7;
    int bb = blockIdx.x >> 8;

    __shared__ float qs[16][64];
    __shared__ float sc[16][512];
    __shared__ float kv[64][65];

    int tid = threadIdx.x;
    {
        int r = tid >> 4, c = (tid & 15) * 4;
        const float* src = QKV + ((size_t)(bb * SEQ + qt * 16 + r) * 1536) + hh * 64 + c;
        *(float4*)(&qs[r][c]) = *(const float4*)src;
    }
    const float scale = 0.125f;
    for (int kt = 0; kt < 8; ++kt) {
        __syncthreads();
#pragma unroll
        for (int j = 0; j < 4; ++j) {
            int idx = tid + j * 256;
            int r = idx >> 4, c = (idx & 15) * 4;
            const float* src = QKV + ((size_t)(bb * SEQ + kt * 64 + r) * 1536) + 512 + hh * 64 + c;
            float4 v4 = *(const float4*)src;
            kv[r][c] = v4.x; kv[r][c + 1] = v4.y; kv[r][c + 2] = v4.z; kv[r][c + 3] = v4.w;
        }
        __syncthreads();
        int kk = tid & 63;
#pragma unroll
        for (int j = 0; j < 4; ++j) {
            int qi = (tid >> 6) + j * 4;
            float s = 0.0f;
#pragma unroll
            for (int d = 0; d < 64; ++d) s = fmaf(qs[qi][d], kv[kk][d], s);
            sc[qi][kt * 64 + kk] = s * scale;
        }
    }
    __syncthreads();

    int lane = tid & 63;
    int w = tid >> 6;
    for (int rr = 0; rr < 4; ++rr) {
        int qi = w + rr * 4;
        float m = -1e30f;
#pragma unroll
        for (int j = 0; j < 8; ++j) m = fmaxf(m, sc[qi][lane + j * 64]);
#pragma unroll
        for (int off = 32; off; off >>= 1) m = fmaxf(m, __shfl_xor(m, off));
        float e[8];
        float sum = 0.0f;
#pragma unroll
        for (int j = 0; j < 8; ++j) { e[j] = __expf(sc[qi][lane + j * 64] - m); sum += e[j]; }
#pragma unroll
        for (int off = 32; off; off >>= 1) sum += __shfl_xor(sum, off);
        float inv = 1.0f / sum;
#pragma unroll
        for (int j = 0; j < 8; ++j) sc[qi][lane + j * 64] = e[j] * inv;
    }

    float acc[4] = {0.f, 0.f, 0.f, 0.f};
    int d = lane;
    for (int vt = 0; vt < 8; ++vt) {
        __syncthreads();
#pragma unroll
        for (int j = 0; j < 4; ++j) {
            int idx = tid + j * 256;
            int r = idx >> 4, c = (idx & 15) * 4;
            const float* src = QKV + ((size_t)(bb * SEQ + vt * 64 + r) * 1536) + 1024 + hh * 64 + c;
            float4 v4 = *(const float4*)src;
            kv[r][c] = v4.x; kv[r][c + 1] = v4.y; kv[r][c + 2] = v4.z; kv[r][c + 3] = v4.w;
        }
        __syncthreads();
#pragma unroll
        for (int j = 0; j < 4; ++j) {
            int qi = w + j * 4;
            float a = 0.0f;
#pragma unroll
            for (int k2 = 0; k2 < 64; ++k2) a = fmaf(sc[qi][vt * 64 + k2], kv[k2][d], a);
            acc[j] += a;
        }
    }
#pragma unroll
    for (int j = 0; j < 4; ++j) {
        int qi = w + j * 4;
        size_t o = ((size_t)(bb * SEQ + qt * 16 + qi) * DMODEL) + hh * 64 + d;
        u16 hv = f2bf(acc[j]);
        Oh[o] = hv;
        Ol[o] = f2bf(acc[j] - bf2f(hv));
    }
}

// ------------------------------------------------------------------------- VQ
// block = 16 rows, 4 waves; wave w owns rows w*4..w*4+3 held in registers
// (lane l holds z[row][l]); codes streamed coalesced from cbT [64][8192];
// z broadcast via readlane -> zero LDS traffic in the inner loop.
__global__ __launch_bounds__(256) void vq2_kernel(
    const float* __restrict__ Z, const float* __restrict__ CBT,
    const float* __restrict__ CB, const float* __restrict__ CBN,
    float* __restrict__ out) {
    __shared__ int ibest[16];
    __shared__ float psum[4][64];
    __shared__ float cl4[4];

    int tid = threadIdx.x;
    int w = tid >> 6, lane = tid & 63;
    int row0 = blockIdx.x * 16;

    float zr[4];
#pragma unroll
    for (int j = 0; j < 4; ++j) zr[j] = Z[(size_t)(row0 + w * 4 + j) * CBD + lane];

    float best[4] = {3.4e38f, 3.4e38f, 3.4e38f, 3.4e38f};
    int bidx[4] = {0, 0, 0, 0};

    for (int ct = 0; ct < CBS; ct += 64) {
        int c = ct + lane;
        float a0 = 0.f, a1 = 0.f, a2 = 0.f, a3 = 0.f;
#pragma unroll
        for (int d = 0; d < 64; ++d) {
            float cv = CBT[(size_t)d * CBS + c];
            float z0 = __int_as_float(__builtin_amdgcn_readlane(__float_as_int(zr[0]), d));
            float z1 = __int_as_float(__builtin_amdgcn_readlane(__float_as_int(zr[1]), d));
            float z2 = __int_as_float(__builtin_amdgcn_readlane(__float_as_int(zr[2]), d));
            float z3 = __int_as_float(__builtin_amdgcn_readlane(__float_as_int(zr[3]), d));
            a0 = fmaf(cv, z0, a0);
            a1 = fmaf(cv, z1, a1);
            a2 = fmaf(cv, z2, a2);
            a3 = fmaf(cv, z3, a3);
        }
        float cn = CBN[c];
        float s0 = cn - 2.f * a0, s1 = cn - 2.f * a1, s2 = cn - 2.f * a2, s3 = cn - 2.f * a3;
        if (s0 < best[0]) { best[0] = s0; bidx[0] = c; }
        if (s1 < best[1]) { best[1] = s1; bidx[1] = c; }
        if (s2 < best[2]) { best[2] = s2; bidx[2] = c; }
        if (s3 < best[3]) { best[3] = s3; bidx[3] = c; }
    }
    // cross-lane argmin (tie -> lower index)
#pragma unroll
    for (int j = 0; j < 4; ++j) {
        float bv = best[j];
        int bi = bidx[j];
#pragma unroll
        for (int off = 32; off; off >>= 1) {
            float ov = __shfl_xor(bv, off);
            int oi = __shfl_xor(bi, off);
            if (ov < bv || (ov == bv && oi < bi)) { bv = ov; bi = oi; }
        }
        if (lane == 0) ibest[w * 4 + j] = bi;
    }
    __syncthreads();

    int d2 = lane;
    float qacc = 0.0f, closs = 0.0f;
#pragma unroll
    for (int j = 0; j < 4; ++j) {
        int r2 = w * 4 + j;
        int bi = ibest[r2];
        float q = CB[(size_t)bi * CBD + d2];
        float z = Z[(size_t)(row0 + r2) * CBD + d2];
        qacc += q;
        float df = q - z;
        closs += df * df;
    }
    psum[w][d2] = qacc;
#pragma unroll
    for (int off = 32; off; off >>= 1) closs += __shfl_xor(closs, off);
    if (d2 == 0) cl4[w] = closs;
    __syncthreads();
    if (tid < 64) {
        float t = psum[0][tid] + psum[1][tid] + psum[2][tid] + psum[3][tid];
        int b = row0 >> 9;
        atomicAdd(out + b * 64 + tid, t);
    }
    if (tid == 0)
        atomicAdd(out + 1024, (cl4[0] + cl4[1] + cl4[2] + cl4[3]) * (1.0f / (float)(MROWS * CBD)));
}

// -------------------------------------------------------------------- launch
extern "C" void kernel_launch(void* const* d_in, const int* in_sizes, int n_in,
                              void* d_out, int out_size, void* d_ws, size_t ws_size,
                              hipStream_t stream) {
    const float* x    = (const float*)d_in[0];
    const float* w_in = (const float*)d_in[1];
    const float* b_in = (const float*)d_in[2];
    const float* pos  = (const float*)d_in[3];
    const float* ln1g = (const float*)d_in[4];
    const float* ln1b = (const float*)d_in[5];
    const float* wq   = (const float*)d_in[6];
    const float* wk   = (const float*)d_in[7];
    const float* wv   = (const float*)d_in[8];
    const float* wo   = (const float*)d_in[9];
    const float* ln2g = (const float*)d_in[10];
    const float* ln2b = (const float*)d_in[11];
    const float* ffw1 = (const float*)d_in[12];
    const float* ffb1 = (const float*)d_in[13];
    const float* ffw2 = (const float*)d_in[14];
    const float* ffb2 = (const float*)d_in[15];
    const float* lnfg = (const float*)d_in[16];
    const float* lnfb = (const float*)d_in[17];
    const float* wout = (const float*)d_in[18];
    const float* bout = (const float*)d_in[19];
    const float* cb   = (const float*)d_in[20];
    float* out = (float*)d_out;

    const size_t MD  = (size_t)MROWS * DMODEL;   // 4,194,304
    const size_t MQ  = (size_t)MROWS * 1536;     // 12,582,912
    const size_t MF  = (size_t)MROWS * DFF;      // 16,777,216

    // ---- workspace layout ----
    float* ws   = (float*)d_ws;
    float* h    = ws;                 // MD f
    float* t0   = h + MD;             // MD f
    float* big  = t0 + MD;            // MF f  (aliased region)
    float* zb   = big + MF;           // MROWS*64 f
    float* cbn  = zb + (size_t)MROWS * CBD;  // 8192 f
    float* cbT  = cbn + CBS;          // 64*8192 f
    u16* t0h    = (u16*)(cbT + (size_t)CBD * CBS); // MD us
    u16* t0l    = t0h + MD;
    u16* wb     = t0l + MD;

    // big aliases
    float* qkv = big;                       // MQ f
    u16* obh   = (u16*)(big + MQ);          // MD us
    u16* obl   = obh + MD;                  // ends at big+MF exactly
    u16* xh    = obh;                       // x split lives here pre-attention
    u16* xl    = obl;
    u16* fmh   = (u16*)big;                 // MF us
    u16* fml   = fmh + MF;                  // ends at big+MF exactly

    // transposed weight planes (ushort), hi then lo per family
    const size_t S_WIN  = (size_t)DMODEL * DMODEL;        // 262144
    const size_t S_QKV  = (size_t)1536 * DMODEL * NDEPTH; // 3145728
    const size_t S_WO   = S_WIN * NDEPTH;                 // 1048576
    const size_t S_FF1  = (size_t)DFF * DMODEL * NDEPTH;  // 4194304
    const size_t S_FF2  = S_FF1;
    u16* winT_h = wb;
    u16* winT_l = winT_h + S_WIN;
    u16* qkvT_h = winT_l + S_WIN;
    u16* qkvT_l = qkvT_h + S_QKV;
    u16* woT_h  = qkvT_l + S_QKV;
    u16* woT_l  = woT_h + S_WO;
    u16* ff1T_h = woT_l + S_WO;
    u16* ff1T_l = ff1T_h + S_FF1;
    u16* ff2T_h = ff1T_l + S_FF1;
    u16* ff2T_l = ff2T_h + S_FF2;

    dim3 blk(256);

    zero_kernel<<<dim3((out_size + 255) / 256), blk, 0, stream>>>(out, out_size);
    cbn_kernel<<<dim3(CBS / 256), blk, 0, stream>>>(cb, cbn);
    // cb [8192][64] -> cbT [64][8192]
    ftrans_kernel<<<dim3(CBD / 32, CBS / 32), blk, 0, stream>>>(cb, cbT, CBS, CBD);

    // weight transposes (+hi/lo split)
    wtrans_kernel<<<dim3(16, 16, 1), blk, 0, stream>>>(w_in, winT_h, winT_l, DMODEL, DMODEL, 0, 0);
    wtrans_kernel<<<dim3(16, 16, NDEPTH), blk, 0, stream>>>(
        wq, qkvT_h, qkvT_l, DMODEL, DMODEL, (long)DMODEL * DMODEL, (long)1536 * DMODEL);
    wtrans_kernel<<<dim3(16, 16, NDEPTH), blk, 0, stream>>>(
        wk, qkvT_h + (size_t)512 * DMODEL, qkvT_l + (size_t)512 * DMODEL,
        DMODEL, DMODEL, (long)DMODEL * DMODEL, (long)1536 * DMODEL);
    wtrans_kernel<<<dim3(16, 16, NDEPTH), blk, 0, stream>>>(
        wv, qkvT_h + (size_t)1024 * DMODEL, qkvT_l + (size_t)1024 * DMODEL,
        DMODEL, DMODEL, (long)DMODEL * DMODEL, (long)1536 * DMODEL);
    wtrans_kernel<<<dim3(16, 16, NDEPTH), blk, 0, stream>>>(
        wo, woT_h, woT_l, DMODEL, DMODEL, (long)DMODEL * DMODEL, (long)DMODEL * DMODEL);
    wtrans_kernel<<<dim3(DFF / 32, 16, NDEPTH), blk, 0, stream>>>(
        ffw1, ff1T_h, ff1T_l, DMODEL, DFF, (long)DMODEL * DFF, (long)DFF * DMODEL);
    wtrans_kernel<<<dim3(16, DFF / 32, NDEPTH), blk, 0, stream>>>(
        ffw2, ff2T_h, ff2T_l, DFF, DMODEL, (long)DFF * DMODEL, (long)DMODEL * DFF);

    // x -> split planes
    split_kernel<<<dim3((int)(MD / 256)), blk, 0, stream>>>(x, xh, xl, (int)MD);

    // input projection + pos emb -> h (fp32)
    gemm3_kernel<<<dim3(MROWS / 128, DMODEL / 128), blk, 0, stream>>>(
        xh, xl, winT_h, winT_l, h, nullptr, nullptr, b_in, nullptr, pos,
        MROWS, DMODEL, DMODEL, 0);

    for (int l = 0; l < NDEPTH; ++l) {
        ln_kernel<<<dim3(MROWS / 4), blk, 0, stream>>>(
            h, t0, t0h, t0l, ln1g + l * DMODEL, ln1b + l * DMODEL);
        // fused QKV: N=1536
        gemm3_kernel<<<dim3(MROWS / 128, 1536 / 128), blk, 0, stream>>>(
            t0h, t0l, qkvT_h + (size_t)l * 1536 * DMODEL, qkvT_l + (size_t)l * 1536 * DMODEL,
            qkv, nullptr, nullptr, nullptr, nullptr, nullptr, MROWS, 1536, DMODEL, 0);
        attn_kernel<<<dim3(BATCH * NHEADS * (SEQ / 16)), blk, 0, stream>>>(qkv, obh, obl);
        gemm3_kernel<<<dim3(MROWS / 128, DMODEL / 128), blk, 0, stream>>>(
            obh, obl, woT_h + (size_t)l * S_WIN, woT_l + (size_t)l * S_WIN,
            h, nullptr, nullptr, nullptr, h, nullptr, MROWS, DMODEL, DMODEL, 0);

        ln_kernel<<<dim3(MROWS / 4), blk, 0, stream>>>(
            h, t0, t0h, t0l, ln2g + l * DMODEL, ln2b + l * DMODEL);
        // ff1 + gelu -> split planes only
        gemm3_kernel<<<dim3(MROWS / 128, DFF / 128), blk, 0, stream>>>(
            t0h, t0l, ff1T_h + (size_t)l * DFF * DMODEL, ff1T_l + (size_t)l * DFF * DMODEL,
            nullptr, fmh, fml, ffb1 + l * DFF, nullptr, nullptr, MROWS, DFF, DMODEL, 1);
        // ff2 + residual -> h
        gemm3_kernel<<<dim3(MROWS / 128, DMODEL / 128), blk, 0, stream>>>(
            fmh, fml, ff2T_h + (size_t)l * DFF * DMODEL, ff2T_l + (size_t)l * DFF * DMODEL,
            h, nullptr, nullptr, ffb2 + l * DMODEL, h, nullptr, MROWS, DMODEL, DFF, 0);
    }

    ln_kernel<<<dim3(MROWS / 4), blk, 0, stream>>>(h, t0, nullptr, nullptr, lnfg, lnfb);
    // out projection in full fp32 (feeds argmin)
    gemm_kernel<<<dim3(MROWS / 64, 1), blk, 0, stream>>>(t0, wout, zb, bout, MROWS, CBD, DMODEL);
    vq2_kernel<<<dim3(MROWS / 16), blk, 0, stream>>>(zb, cbT, cb, cbn, out);
}

// Round 3
// 2679.174 us; speedup vs baseline: 2.1320x; 1.4792x over previous
//
#include <hip/hip_runtime.h>
#include <cmath>

#define BATCH 16
#define SEQ 512
#define DMODEL 512
#define NDEPTH 4
#define NHEADS 8
#define DHEAD 64
#define DFF 2048
#define CBD 64
#define CBS 8192
#define MROWS (BATCH * SEQ) // 8192

typedef unsigned short u16;
typedef __attribute__((ext_vector_type(8))) short short8; // 8 bf16 = 4 VGPRs (MFMA A/B frag)
typedef __attribute__((ext_vector_type(4))) float f32x4;  // MFMA C/D frag
typedef __attribute__((ext_vector_type(4))) unsigned short u16x4;

// ---------------------------------------------------------------- bf16 helpers
__device__ __forceinline__ u16 f2bf(float f) {
    unsigned u = __float_as_uint(f);
    u += 0x7fff + ((u >> 16) & 1); // RNE
    return (u16)(u >> 16);
}
__device__ __forceinline__ float bf2f(u16 h) {
    return __uint_as_float(((unsigned)h) << 16);
}

// async global->LDS 16B: LDS dest must be wave-uniform base + lane*16
__device__ __forceinline__ void async16(u16* lds, const u16* g) {
    __builtin_amdgcn_global_load_lds(
        (const __attribute__((address_space(1))) unsigned int*)g,
        (__attribute__((address_space(3))) unsigned int*)lds, 16, 0, 0);
}

__device__ __forceinline__ float gelu_tanh(float u) {
    return 0.5f * u * (1.0f + tanhf(0.7978845608028654f * (u + 0.044715f * u * u * u)));
}

// ---------------------------------------------------------------- zero output
__global__ void zero_kernel(float* __restrict__ p, int n) {
    int i = blockIdx.x * 256 + threadIdx.x;
    if (i < n) p[i] = 0.0f;
}

// ------------------------------------------------------------- codebook norms
__global__ void cbn_kernel(const float* __restrict__ cb, float* __restrict__ cbn) {
    int c = blockIdx.x * 256 + threadIdx.x;
    if (c >= CBS) return;
    const float* row = cb + (size_t)c * CBD;
    float s = 0.0f;
#pragma unroll
    for (int d = 0; d < CBD; ++d) s += row[d] * row[d];
    cbn[c] = s;
}

// ------------------------------------------- fp32 transpose (codebook -> cbT)
__global__ __launch_bounds__(256) void ftrans_kernel(
    const float* __restrict__ W, float* __restrict__ T, int K, int N) {
    __shared__ float t[32][33];
    int n0 = blockIdx.x * 32, k0 = blockIdx.y * 32;
    int tx = threadIdx.x & 31, ty = threadIdx.x >> 5;
#pragma unroll
    for (int r = ty; r < 32; r += 8) t[r][tx] = W[(size_t)(k0 + r) * N + n0 + tx];
    __syncthreads();
#pragma unroll
    for (int r = ty; r < 32; r += 8) T[(size_t)(n0 + r) * K + k0 + tx] = t[tx][r];
}

// ------------------------- weight transpose + split: W [z][K][N] -> T [z][N][K]
__global__ __launch_bounds__(256) void wtrans_kernel(
    const float* __restrict__ W, u16* __restrict__ Th, u16* __restrict__ Tl,
    int K, int N, long inLS, long outLS) {
    __shared__ float t[32][33];
    const float* Ws = W + (size_t)blockIdx.z * inLS;
    u16* Tho = Th + (size_t)blockIdx.z * outLS;
    u16* Tlo = Tl + (size_t)blockIdx.z * outLS;
    int n0 = blockIdx.x * 32, k0 = blockIdx.y * 32;
    int tx = threadIdx.x & 31, ty = threadIdx.x >> 5;
#pragma unroll
    for (int r = ty; r < 32; r += 8) t[r][tx] = Ws[(size_t)(k0 + r) * N + n0 + tx];
    __syncthreads();
#pragma unroll
    for (int r = ty; r < 32; r += 8) {
        float v = t[tx][r];
        size_t o = (size_t)(n0 + r) * K + k0 + tx;
        u16 hh = f2bf(v);
        Tho[o] = hh;
        Tlo[o] = f2bf(v - bf2f(hh));
    }
}

// ------------------------ u16 transpose for V: qkv planes -> VT [b][512d][512s]
__global__ __launch_bounds__(256) void vtrans_kernel(
    const u16* __restrict__ Qh, const u16* __restrict__ Ql,
    u16* __restrict__ VTh, u16* __restrict__ VTl) {
    __shared__ u16 t[64][68];
    int s0 = blockIdx.x * 64, d0 = blockIdx.y * 64;
    int b = blockIdx.z & 15, plane = blockIdx.z >> 4;
    const u16* src = (plane ? Ql : Qh);
    u16* dst = (plane ? VTl : VTh);
    int tid = threadIdx.x;
    int rr = tid >> 4, c4 = (tid & 15) * 4;
#pragma unroll
    for (int i = 0; i < 4; ++i) {
        int r = rr + i * 16;
        const u16* p = src + (size_t)(b * SEQ + s0 + r) * 1536 + 1024 + d0 + c4;
        *(u16x4*)(&t[r][c4]) = *(const u16x4*)p;
    }
    __syncthreads();
#pragma unroll
    for (int i = 0; i < 4; ++i) {
        int r = rr + i * 16; // d-index within tile
        u16x4 v;
        v.x = t[c4 + 0][r]; v.y = t[c4 + 1][r]; v.z = t[c4 + 2][r]; v.w = t[c4 + 3][r];
        *(u16x4*)(dst + (size_t)b * SEQ * DMODEL + (size_t)(d0 + r) * SEQ + s0 + c4) = v;
    }
}

// ------------------------------------------------ elementwise fp32 -> (hi,lo)
__global__ void split_kernel(const float* __restrict__ X, u16* __restrict__ H,
                             u16* __restrict__ L, int n) {
    int i = blockIdx.x * 256 + threadIdx.x;
    if (i < n) {
        float v = X[i];
        u16 hh = f2bf(v);
        H[i] = hh;
        L[i] = f2bf(v - bf2f(hh));
    }
}

// ------------------------------------------------------------------ layernorm
__global__ __launch_bounds__(256) void ln_kernel(
    const float* __restrict__ X, float* __restrict__ Y,
    u16* __restrict__ Yh, u16* __restrict__ Yl,
    const float* __restrict__ g, const float* __restrict__ b) {
    int row  = blockIdx.x * 4 + (threadIdx.x >> 6);
    int lane = threadIdx.x & 63;
    const float* x = X + (size_t)row * DMODEL;
    float v[8];
    float s = 0.0f;
#pragma unroll
    for (int j = 0; j < 8; ++j) { v[j] = x[lane + j * 64]; s += v[j]; }
#pragma unroll
    for (int off = 32; off; off >>= 1) s += __shfl_xor(s, off);
    float mu  = s * (1.0f / DMODEL);
    float var = 0.0f;
#pragma unroll
    for (int j = 0; j < 8; ++j) { float d = v[j] - mu; var += d * d; }
#pragma unroll
    for (int off = 32; off; off >>= 1) var += __shfl_xor(var, off);
    float r = rsqrtf(var * (1.0f / DMODEL) + 1e-5f);
#pragma unroll
    for (int j = 0; j < 8; ++j) {
        int d = lane + j * 64;
        float y = (v[j] - mu) * r * g[d] + b[d];
        size_t o = (size_t)row * DMODEL + d;
        Y[o] = y;
        if (Yh) {
            u16 hh = f2bf(y);
            Yh[o] = hh;
            Yl[o] = f2bf(y - bf2f(hh));
        }
    }
}

// --------------------------------------------------------- bf16x3 MFMA GEMM
__global__ __launch_bounds__(256) void gemm3_kernel(
    const u16* __restrict__ Ah, const u16* __restrict__ Al,
    const u16* __restrict__ Bh, const u16* __restrict__ Bl,
    float* __restrict__ Cf, u16* __restrict__ Ch, u16* __restrict__ Cl,
    const float* __restrict__ bias, const float* __restrict__ res,
    const float* __restrict__ pos, int M, int N, int K, int gelu) {
    __shared__ __align__(16) u16 AsU[128 * 32];
    __shared__ __align__(16) u16 BsU[128 * 32];

    int tid  = threadIdx.x;
    int w    = tid >> 6, lane = tid & 63;
    int wr   = w >> 1, wc = w & 1;
    int quad = lane >> 4, l16 = lane & 15;
    int m0   = blockIdx.x * 128;
    int n0   = blockIdx.y * 128;

    f32x4 acc[4][4];
#pragma unroll
    for (int i = 0; i < 4; ++i)
#pragma unroll
        for (int j = 0; j < 4; ++j) acc[i][j] = (f32x4){0.f, 0.f, 0.f, 0.f};

    int off0 = tid * 16;
    int row0s = off0 >> 6, ke0 = (off0 & 63) >> 1;
    int off1 = 4096 + tid * 16;
    int row1s = off1 >> 6, ke1 = (off1 & 63) >> 1;

#pragma unroll
    for (int pass = 0; pass < 3; ++pass) {
        const u16* Ap = (pass == 1) ? Al : Ah;
        const u16* Bp = (pass == 2) ? Bl : Bh;
        const u16* Abase = Ap + (size_t)m0 * K;
        const u16* Bbase = Bp + (size_t)n0 * K;
        for (int ks = 0; ks < K; ks += 32) {
            __syncthreads();
            async16(&AsU[off0 >> 1], Abase + (size_t)row0s * K + ks + ke0);
            async16(&BsU[off0 >> 1], Bbase + (size_t)row0s * K + ks + ke0);
            async16(&AsU[off1 >> 1], Abase + (size_t)row1s * K + ks + ke1);
            async16(&BsU[off1 >> 1], Bbase + (size_t)row1s * K + ks + ke1);
            __syncthreads();
            short8 af[4], bf[4];
#pragma unroll
            for (int i = 0; i < 4; ++i)
                af[i] = *(const short8*)&AsU[(wr * 64 + i * 16 + l16) * 32 + quad * 8];
#pragma unroll
            for (int i = 0; i < 4; ++i)
                bf[i] = *(const short8*)&BsU[(wc * 64 + i * 16 + l16) * 32 + quad * 8];
#pragma unroll
            for (int i = 0; i < 4; ++i)
#pragma unroll
                for (int j = 0; j < 4; ++j)
                    acc[i][j] = __builtin_amdgcn_mfma_f32_16x16x32_bf16(af[i], bf[j], acc[i][j], 0, 0, 0);
        }
    }

    int mbase = m0 + wr * 64;
    int nbase = n0 + wc * 64;
#pragma unroll
    for (int mi = 0; mi < 4; ++mi)
#pragma unroll
        for (int ni = 0; ni < 4; ++ni) {
            f32x4 a = acc[mi][ni];
#pragma unroll
            for (int r = 0; r < 4; ++r) {
                int m = mbase + mi * 16 + quad * 4 + r;
                int n = nbase + ni * 16 + l16;
                float v = a[r];
                if (bias) v += bias[n];
                if (pos)  v += pos[(size_t)(m & (SEQ - 1)) * N + n];
                if (res)  v += res[(size_t)m * N + n];
                if (gelu) v = gelu_tanh(v);
                size_t o = (size_t)m * N + n;
                if (Cf) Cf[o] = v;
                if (Ch) {
                    u16 hh = f2bf(v);
                    Ch[o] = hh;
                    Cl[o] = f2bf(v - bf2f(hh));
                }
            }
        }
}

// ------------------------------------------------------------ fp32 GEMM (small)
__global__ __launch_bounds__(256) void gemm_kernel(
    const float* __restrict__ A, const float* __restrict__ Bm,
    float* __restrict__ C, const float* __restrict__ bias,
    int M, int N, int K) {
    __shared__ float As[16][68];
    __shared__ float Bs[16][64];
    int tid = threadIdx.x;
    int tx = tid & 15, ty = tid >> 4;
    int a_m = tid >> 2, a_k = (tid & 3) * 4;
    int b_k = tid >> 4, b_n = (tid & 15) * 4;
    const float* Arow = A + (size_t)(blockIdx.x * 64 + a_m) * K;
    const float* Bcol = Bm + (size_t)blockIdx.y * 64 + b_n;
    float acc[4][4] = {};
    for (int k0 = 0; k0 < K; k0 += 16) {
        float4 av = *(const float4*)(Arow + k0 + a_k);
        float4 bv = *(const float4*)(Bcol + (size_t)(k0 + b_k) * N);
        __syncthreads();
        As[a_k + 0][a_m] = av.x; As[a_k + 1][a_m] = av.y;
        As[a_k + 2][a_m] = av.z; As[a_k + 3][a_m] = av.w;
        *(float4*)(&Bs[b_k][b_n]) = bv;
        __syncthreads();
#pragma unroll
        for (int kk = 0; kk < 16; ++kk) {
            float4 a4 = *(const float4*)(&As[kk][ty * 4]);
            float4 b4 = *(const float4*)(&Bs[kk][tx * 4]);
            float ar[4] = {a4.x, a4.y, a4.z, a4.w};
            float br[4] = {b4.x, b4.y, b4.z, b4.w};
#pragma unroll
            for (int i = 0; i < 4; ++i)
#pragma unroll
                for (int j = 0; j < 4; ++j) acc[i][j] = fmaf(ar[i], br[j], acc[i][j]);
        }
    }
    int m0 = blockIdx.x * 64 + ty * 4;
    int n0 = blockIdx.y * 64 + tx * 4;
#pragma unroll
    for (int i = 0; i < 4; ++i) {
        float vv[4];
#pragma unroll
        for (int j = 0; j < 4; ++j) {
            float t = acc[i][j];
            if (bias) t += bias[n0 + j];
            vv[j] = t;
        }
        *(float4*)(C + (size_t)(m0 + i) * N + n0) = make_float4(vv[0], vv[1], vv[2], vv[3]);
    }
}

// ----------------------------------------------------------- MFMA attention
// block = (b, h, 16-query tile), 4 waves. bf16x3-split QK^T and PV via MFMA.
// LDS union: phase 1 scores fp32 [16][512]; phase 2 Ph/Pl u16 [16][544].
__global__ __launch_bounds__(256) void attn_mfma_kernel(
    const u16* __restrict__ QKh, const u16* __restrict__ QKl,
    const u16* __restrict__ VTh, const u16* __restrict__ VTl,
    u16* __restrict__ Oh, u16* __restrict__ Ol) {
    int qt = blockIdx.x & 31;
    int hh = (blockIdx.x >> 5) & 7;
    int bb = blockIdx.x >> 8;

    __shared__ __align__(16) unsigned char ldsbuf[16 * 544 * 2 * 2]; // 34816 B
    float* sc = (float*)ldsbuf;       // [16][512] fp32
    u16* Ph = (u16*)ldsbuf;           // [16][544]
    u16* Pl = Ph + 16 * 544;

    int tid = threadIdx.x;
    int w = tid >> 6, lane = tid & 63;
    int quad = lane >> 4, l16 = lane & 15;

    // ---- Q fragments (A-layout: m=l16, k=quad*8+j; 2 k-steps over d=64)
    const u16* qrh = QKh + (size_t)(bb * SEQ + qt * 16 + l16) * 1536 + hh * 64 + quad * 8;
    const u16* qrl = QKl + (size_t)(bb * SEQ + qt * 16 + l16) * 1536 + hh * 64 + quad * 8;
    short8 Qh0 = *(const short8*)qrh;
    short8 Qh1 = *(const short8*)(qrh + 32);
    short8 Ql0 = *(const short8*)qrl;
    short8 Ql1 = *(const short8*)(qrl + 32);

    // ---- S = QK^T: wave w covers keys kt*64 + w*16 + [0,16)
    for (int kt = 0; kt < 8; ++kt) {
        int krow = bb * SEQ + kt * 64 + w * 16 + l16;
        const u16* krh = QKh + (size_t)krow * 1536 + 512 + hh * 64 + quad * 8;
        const u16* krl = QKl + (size_t)krow * 1536 + 512 + hh * 64 + quad * 8;
        short8 Kh0 = *(const short8*)krh;
        short8 Kh1 = *(const short8*)(krh + 32);
        short8 Kl0 = *(const short8*)krl;
        short8 Kl1 = *(const short8*)(krl + 32);
        f32x4 a = (f32x4){0.f, 0.f, 0.f, 0.f};
        a = __builtin_amdgcn_mfma_f32_16x16x32_bf16(Qh0, Kh0, a, 0, 0, 0);
        a = __builtin_amdgcn_mfma_f32_16x16x32_bf16(Qh1, Kh1, a, 0, 0, 0);
        a = __builtin_amdgcn_mfma_f32_16x16x32_bf16(Ql0, Kh0, a, 0, 0, 0);
        a = __builtin_amdgcn_mfma_f32_16x16x32_bf16(Ql1, Kh1, a, 0, 0, 0);
        a = __builtin_amdgcn_mfma_f32_16x16x32_bf16(Qh0, Kl0, a, 0, 0, 0);
        a = __builtin_amdgcn_mfma_f32_16x16x32_bf16(Qh1, Kl1, a, 0, 0, 0);
        int key = kt * 64 + w * 16 + l16;
#pragma unroll
        for (int r = 0; r < 4; ++r)
            sc[(quad * 4 + r) * 512 + key] = a[r] * 0.125f; // C layout: row=quad*4+r, col=l16
    }
    __syncthreads();

    // ---- softmax: wave w owns rows {w, w+4, w+8, w+12}; keys in regs
    float e[4][8];
#pragma unroll
    for (int rr = 0; rr < 4; ++rr) {
        int qi = w + rr * 4;
        float m = -1e30f;
#pragma unroll
        for (int j = 0; j < 8; ++j) { e[rr][j] = sc[qi * 512 + lane + j * 64]; m = fmaxf(m, e[rr][j]); }
#pragma unroll
        for (int off = 32; off; off >>= 1) m = fmaxf(m, __shfl_xor(m, off));
        float sum = 0.0f;
#pragma unroll
        for (int j = 0; j < 8; ++j) { e[rr][j] = __expf(e[rr][j] - m); sum += e[rr][j]; }
#pragma unroll
        for (int off = 32; off; off >>= 1) sum += __shfl_xor(sum, off);
        float inv = 1.0f / sum;
#pragma unroll
        for (int j = 0; j < 8; ++j) e[rr][j] *= inv;
    }
    __syncthreads(); // all sc reads done before Ph/Pl overwrite

#pragma unroll
    for (int rr = 0; rr < 4; ++rr) {
        int qi = w + rr * 4;
#pragma unroll
        for (int j = 0; j < 8; ++j) {
            float v = e[rr][j];
            u16 hv = f2bf(v);
            Ph[qi * 544 + lane + j * 64] = hv;
            Pl[qi * 544 + lane + j * 64] = f2bf(v - bf2f(hv));
        }
    }
    __syncthreads();

    // ---- O = P V: wave w owns d-range [w*16, w*16+16); 16 k-steps of 32 keys
    const u16* vth = VTh + ((size_t)bb * SEQ + hh * 64 + w * 16 + l16) * SEQ + quad * 8;
    const u16* vtl = VTl + ((size_t)bb * SEQ + hh * 64 + w * 16 + l16) * SEQ + quad * 8;
    const u16* ph = Ph + l16 * 544 + quad * 8;
    const u16* pl = Pl + l16 * 544 + quad * 8;
    f32x4 acc0 = (f32x4){0.f, 0.f, 0.f, 0.f};
    f32x4 acc1 = (f32x4){0.f, 0.f, 0.f, 0.f};
#pragma unroll
    for (int ks = 0; ks < 512; ks += 64) {
        short8 P0h = *(const short8*)(ph + ks);
        short8 P0l = *(const short8*)(pl + ks);
        short8 V0h = *(const short8*)(vth + ks);
        short8 V0l = *(const short8*)(vtl + ks);
        short8 P1h = *(const short8*)(ph + ks + 32);
        short8 P1l = *(const short8*)(pl + ks + 32);
        short8 V1h = *(const short8*)(vth + ks + 32);
        short8 V1l = *(const short8*)(vtl + ks + 32);
        acc0 = __builtin_amdgcn_mfma_f32_16x16x32_bf16(P0h, V0h, acc0, 0, 0, 0);
        acc1 = __builtin_amdgcn_mfma_f32_16x16x32_bf16(P1h, V1h, acc1, 0, 0, 0);
        acc0 = __builtin_amdgcn_mfma_f32_16x16x32_bf16(P0l, V0h, acc0, 0, 0, 0);
        acc1 = __builtin_amdgcn_mfma_f32_16x16x32_bf16(P1l, V1h, acc1, 0, 0, 0);
        acc0 = __builtin_amdgcn_mfma_f32_16x16x32_bf16(P0h, V0l, acc0, 0, 0, 0);
        acc1 = __builtin_amdgcn_mfma_f32_16x16x32_bf16(P1h, V1l, acc1, 0, 0, 0);
    }
    f32x4 o = acc0 + acc1;
#pragma unroll
    for (int r = 0; r < 4; ++r) {
        int q = quad * 4 + r;
        size_t off = (size_t)(bb * SEQ + qt * 16 + q) * DMODEL + hh * 64 + w * 16 + l16;
        u16 hv = f2bf(o[r]);
        Oh[off] = hv;
        Ol[off] = f2bf(o[r] - bf2f(hv));
    }
}

// ------------------------------------------------------------------------- VQ
__global__ __launch_bounds__(256) void vq2_kernel(
    const float* __restrict__ Z, const float* __restrict__ CBT,
    const float* __restrict__ CB, const float* __restrict__ CBN,
    float* __restrict__ out) {
    __shared__ int ibest[16];
    __shared__ float psum[4][64];
    __shared__ float cl4[4];

    int tid = threadIdx.x;
    int w = tid >> 6, lane = tid & 63;
    int row0 = blockIdx.x * 16;

    float zr[4];
#pragma unroll
    for (int j = 0; j < 4; ++j) zr[j] = Z[(size_t)(row0 + w * 4 + j) * CBD + lane];

    float best[4] = {3.4e38f, 3.4e38f, 3.4e38f, 3.4e38f};
    int bidx[4] = {0, 0, 0, 0};

    for (int ct = 0; ct < CBS; ct += 64) {
        int c = ct + lane;
        float a0 = 0.f, a1 = 0.f, a2 = 0.f, a3 = 0.f;
#pragma unroll
        for (int d = 0; d < 64; ++d) {
            float cv = CBT[(size_t)d * CBS + c];
            float z0 = __int_as_float(__builtin_amdgcn_readlane(__float_as_int(zr[0]), d));
            float z1 = __int_as_float(__builtin_amdgcn_readlane(__float_as_int(zr[1]), d));
            float z2 = __int_as_float(__builtin_amdgcn_readlane(__float_as_int(zr[2]), d));
            float z3 = __int_as_float(__builtin_amdgcn_readlane(__float_as_int(zr[3]), d));
            a0 = fmaf(cv, z0, a0);
            a1 = fmaf(cv, z1, a1);
            a2 = fmaf(cv, z2, a2);
            a3 = fmaf(cv, z3, a3);
        }
        float cn = CBN[c];
        float s0 = cn - 2.f * a0, s1 = cn - 2.f * a1, s2 = cn - 2.f * a2, s3 = cn - 2.f * a3;
        if (s0 < best[0]) { best[0] = s0; bidx[0] = c; }
        if (s1 < best[1]) { best[1] = s1; bidx[1] = c; }
        if (s2 < best[2]) { best[2] = s2; bidx[2] = c; }
        if (s3 < best[3]) { best[3] = s3; bidx[3] = c; }
    }
#pragma unroll
    for (int j = 0; j < 4; ++j) {
        float bv = best[j];
        int bi = bidx[j];
#pragma unroll
        for (int off = 32; off; off >>= 1) {
            float ov = __shfl_xor(bv, off);
            int oi = __shfl_xor(bi, off);
            if (ov < bv || (ov == bv && oi < bi)) { bv = ov; bi = oi; }
        }
        if (lane == 0) ibest[w * 4 + j] = bi;
    }
    __syncthreads();

    int d2 = lane;
    float qacc = 0.0f, closs = 0.0f;
#pragma unroll
    for (int j = 0; j < 4; ++j) {
        int r2 = w * 4 + j;
        int bi = ibest[r2];
        float q = CB[(size_t)bi * CBD + d2];
        float z = Z[(size_t)(row0 + r2) * CBD + d2];
        qacc += q;
        float df = q - z;
        closs += df * df;
    }
    psum[w][d2] = qacc;
#pragma unroll
    for (int off = 32; off; off >>= 1) closs += __shfl_xor(closs, off);
    if (d2 == 0) cl4[w] = closs;
    __syncthreads();
    if (tid < 64) {
        float t = psum[0][tid] + psum[1][tid] + psum[2][tid] + psum[3][tid];
        int b = row0 >> 9;
        atomicAdd(out + b * 64 + tid, t);
    }
    if (tid == 0)
        atomicAdd(out + 1024, (cl4[0] + cl4[1] + cl4[2] + cl4[3]) * (1.0f / (float)(MROWS * CBD)));
}

// -------------------------------------------------------------------- launch
extern "C" void kernel_launch(void* const* d_in, const int* in_sizes, int n_in,
                              void* d_out, int out_size, void* d_ws, size_t ws_size,
                              hipStream_t stream) {
    const float* x    = (const float*)d_in[0];
    const float* w_in = (const float*)d_in[1];
    const float* b_in = (const float*)d_in[2];
    const float* pos  = (const float*)d_in[3];
    const float* ln1g = (const float*)d_in[4];
    const float* ln1b = (const float*)d_in[5];
    const float* wq   = (const float*)d_in[6];
    const float* wk   = (const float*)d_in[7];
    const float* wv   = (const float*)d_in[8];
    const float* wo   = (const float*)d_in[9];
    const float* ln2g = (const float*)d_in[10];
    const float* ln2b = (const float*)d_in[11];
    const float* ffw1 = (const float*)d_in[12];
    const float* ffb1 = (const float*)d_in[13];
    const float* ffw2 = (const float*)d_in[14];
    const float* ffb2 = (const float*)d_in[15];
    const float* lnfg = (const float*)d_in[16];
    const float* lnfb = (const float*)d_in[17];
    const float* wout = (const float*)d_in[18];
    const float* bout = (const float*)d_in[19];
    const float* cb   = (const float*)d_in[20];
    float* out = (float*)d_out;

    const size_t MD  = (size_t)MROWS * DMODEL;   // 4,194,304
    const size_t MQ  = (size_t)MROWS * 1536;     // 12,582,912
    const size_t MF  = (size_t)MROWS * DFF;      // 16,777,216

    float* ws   = (float*)d_ws;
    float* h    = ws;
    float* t0   = h + MD;
    float* big  = t0 + MD;                   // MF floats (aliased region)
    float* zb   = big + MF;
    float* cbn  = zb + (size_t)MROWS * CBD;
    float* cbT  = cbn + CBS;
    u16* t0h    = (u16*)(cbT + (size_t)CBD * CBS);
    u16* t0l    = t0h + MD;
    u16* wb     = t0l + MD;

    // big aliases: attention phase = qkvh|qkvl|obh|obl (u16), exactly MF floats
    u16* qkvh = (u16*)big;
    u16* qkvl = qkvh + MQ;
    u16* obh  = qkvl + MQ;
    u16* obl  = obh + MD;
    u16* xh   = obh; // input split (pre-attention use)
    u16* xl   = obl;
    u16* fmh  = (u16*)big; // FF phase
    u16* fml  = fmh + MF;

    const size_t S_WIN  = (size_t)DMODEL * DMODEL;
    const size_t S_QKV  = (size_t)1536 * DMODEL * NDEPTH;
    const size_t S_WO   = S_WIN * NDEPTH;
    const size_t S_FF1  = (size_t)DFF * DMODEL * NDEPTH;
    const size_t S_FF2  = S_FF1;
    u16* winT_h = wb;
    u16* winT_l = winT_h + S_WIN;
    u16* qkvT_h = winT_l + S_WIN;
    u16* qkvT_l = qkvT_h + S_QKV;
    u16* woT_h  = qkvT_l + S_QKV;
    u16* woT_l  = woT_h + S_WO;
    u16* ff1T_h = woT_l + S_WO;
    u16* ff1T_l = ff1T_h + S_FF1;
    u16* ff2T_h = ff1T_l + S_FF1;
    u16* ff2T_l = ff2T_h + S_FF2;
    // V transpose planes (new): [16][512][512] u16 each
    u16* VTh = ff2T_l + S_FF2;
    u16* VTl = VTh + (size_t)BATCH * SEQ * DMODEL;

    dim3 blk(256);

    zero_kernel<<<dim3((out_size + 255) / 256), blk, 0, stream>>>(out, out_size);
    cbn_kernel<<<dim3(CBS / 256), blk, 0, stream>>>(cb, cbn);
    ftrans_kernel<<<dim3(CBD / 32, CBS / 32), blk, 0, stream>>>(cb, cbT, CBS, CBD);

    wtrans_kernel<<<dim3(16, 16, 1), blk, 0, stream>>>(w_in, winT_h, winT_l, DMODEL, DMODEL, 0, 0);
    wtrans_kernel<<<dim3(16, 16, NDEPTH), blk, 0, stream>>>(
        wq, qkvT_h, qkvT_l, DMODEL, DMODEL, (long)DMODEL * DMODEL, (long)1536 * DMODEL);
    wtrans_kernel<<<dim3(16, 16, NDEPTH), blk, 0, stream>>>(
        wk, qkvT_h + (size_t)512 * DMODEL, qkvT_l + (size_t)512 * DMODEL,
        DMODEL, DMODEL, (long)DMODEL * DMODEL, (long)1536 * DMODEL);
    wtrans_kernel<<<dim3(16, 16, NDEPTH), blk, 0, stream>>>(
        wv, qkvT_h + (size_t)1024 * DMODEL, qkvT_l + (size_t)1024 * DMODEL,
        DMODEL, DMODEL, (long)DMODEL * DMODEL, (long)1536 * DMODEL);
    wtrans_kernel<<<dim3(16, 16, NDEPTH), blk, 0, stream>>>(
        wo, woT_h, woT_l, DMODEL, DMODEL, (long)DMODEL * DMODEL, (long)DMODEL * DMODEL);
    wtrans_kernel<<<dim3(DFF / 32, 16, NDEPTH), blk, 0, stream>>>(
        ffw1, ff1T_h, ff1T_l, DMODEL, DFF, (long)DMODEL * DFF, (long)DFF * DMODEL);
    wtrans_kernel<<<dim3(16, DFF / 32, NDEPTH), blk, 0, stream>>>(
        ffw2, ff2T_h, ff2T_l, DFF, DMODEL, (long)DFF * DMODEL, (long)DMODEL * DFF);

    split_kernel<<<dim3((int)(MD / 256)), blk, 0, stream>>>(x, xh, xl, (int)MD);

    gemm3_kernel<<<dim3(MROWS / 128, DMODEL / 128), blk, 0, stream>>>(
        xh, xl, winT_h, winT_l, h, nullptr, nullptr, b_in, nullptr, pos,
        MROWS, DMODEL, DMODEL, 0);

    for (int l = 0; l < NDEPTH; ++l) {
        ln_kernel<<<dim3(MROWS / 4), blk, 0, stream>>>(
            h, t0, t0h, t0l, ln1g + l * DMODEL, ln1b + l * DMODEL);
        // fused QKV -> split bf16 planes directly
        gemm3_kernel<<<dim3(MROWS / 128, 1536 / 128), blk, 0, stream>>>(
            t0h, t0l, qkvT_h + (size_t)l * 1536 * DMODEL, qkvT_l + (size_t)l * 1536 * DMODEL,
            nullptr, qkvh, qkvl, nullptr, nullptr, nullptr, MROWS, 1536, DMODEL, 0);
        // V -> VT planes
        vtrans_kernel<<<dim3(8, 8, 32), blk, 0, stream>>>(qkvh, qkvl, VTh, VTl);
        attn_mfma_kernel<<<dim3(BATCH * NHEADS * (SEQ / 16)), blk, 0, stream>>>(
            qkvh, qkvl, VTh, VTl, obh, obl);
        gemm3_kernel<<<dim3(MROWS / 128, DMODEL / 128), blk, 0, stream>>>(
            obh, obl, woT_h + (size_t)l * S_WIN, woT_l + (size_t)l * S_WIN,
            h, nullptr, nullptr, nullptr, h, nullptr, MROWS, DMODEL, DMODEL, 0);

        ln_kernel<<<dim3(MROWS / 4), blk, 0, stream>>>(
            h, t0, t0h, t0l, ln2g + l * DMODEL, ln2b + l * DMODEL);
        gemm3_kernel<<<dim3(MROWS / 128, DFF / 128), blk, 0, stream>>>(
            t0h, t0l, ff1T_h + (size_t)l * DFF * DMODEL, ff1T_l + (size_t)l * DFF * DMODEL,
            nullptr, fmh, fml, ffb1 + l * DFF, nullptr, nullptr, MROWS, DFF, DMODEL, 1);
        gemm3_kernel<<<dim3(MROWS / 128, DMODEL / 128), blk, 0, stream>>>(
            fmh, fml, ff2T_h + (size_t)l * DFF * DMODEL, ff2T_l + (size_t)l * DFF * DMODEL,
            h, nullptr, nullptr, ffb2 + l * DMODEL, h, nullptr, MROWS, DMODEL, DFF, 0);
    }

    ln_kernel<<<dim3(MROWS / 4), blk, 0, stream>>>(h, t0, nullptr, nullptr, lnfg, lnfb);
    gemm_kernel<<<dim3(MROWS / 64, 1), blk, 0, stream>>>(t0, wout, zb, bout, MROWS, CBD, DMODEL);
    vq2_kernel<<<dim3(MROWS / 16), blk, 0, stream>>>(zb, cbT, cb, cbn, out);
}

// Round 4
// 2428.432 us; speedup vs baseline: 2.3522x; 1.1033x over previous
//
#include <hip/hip_runtime.h>
#include <cmath>

#define BATCH 16
#define SEQ 512
#define DMODEL 512
#define NDEPTH 4
#define NHEADS 8
#define DHEAD 64
#define DFF 2048
#define CBD 64
#define CBS 8192
#define MROWS (BATCH * SEQ) // 8192

typedef unsigned short u16;
typedef __attribute__((ext_vector_type(8))) short short8; // 8 bf16 = 4 VGPRs (MFMA A/B frag)
typedef __attribute__((ext_vector_type(4))) float f32x4;  // MFMA C/D frag
typedef __attribute__((ext_vector_type(4))) unsigned short u16x4;

// ---------------------------------------------------------------- bf16 helpers
__device__ __forceinline__ u16 f2bf(float f) {
    unsigned u = __float_as_uint(f);
    u += 0x7fff + ((u >> 16) & 1); // RNE
    return (u16)(u >> 16);
}
__device__ __forceinline__ float bf2f(u16 h) {
    return __uint_as_float(((unsigned)h) << 16);
}

// async global->LDS 16B: LDS dest must be wave-uniform base + lane*16
__device__ __forceinline__ void async16(u16* lds, const u16* g) {
    __builtin_amdgcn_global_load_lds(
        (const __attribute__((address_space(1))) unsigned int*)g,
        (__attribute__((address_space(3))) unsigned int*)lds, 16, 0, 0);
}

__device__ __forceinline__ float gelu_tanh(float u) {
    return 0.5f * u * (1.0f + tanhf(0.7978845608028654f * (u + 0.044715f * u * u * u)));
}

// ---------------------------------------------------------------- zero output
__global__ void zero_kernel(float* __restrict__ p, int n) {
    int i = blockIdx.x * 256 + threadIdx.x;
    if (i < n) p[i] = 0.0f;
}

// ------------------------------------------------------------- codebook norms
__global__ void cbn_kernel(const float* __restrict__ cb, float* __restrict__ cbn) {
    int c = blockIdx.x * 256 + threadIdx.x;
    if (c >= CBS) return;
    const float* row = cb + (size_t)c * CBD;
    float s = 0.0f;
#pragma unroll
    for (int d = 0; d < CBD; ++d) s += row[d] * row[d];
    cbn[c] = s;
}

// ------------------------- weight transpose + split: W [z][K][N] -> T [z][N][K]
__global__ __launch_bounds__(256) void wtrans_kernel(
    const float* __restrict__ W, u16* __restrict__ Th, u16* __restrict__ Tl,
    int K, int N, long inLS, long outLS) {
    __shared__ float t[32][33];
    const float* Ws = W + (size_t)blockIdx.z * inLS;
    u16* Tho = Th + (size_t)blockIdx.z * outLS;
    u16* Tlo = Tl + (size_t)blockIdx.z * outLS;
    int n0 = blockIdx.x * 32, k0 = blockIdx.y * 32;
    int tx = threadIdx.x & 31, ty = threadIdx.x >> 5;
#pragma unroll
    for (int r = ty; r < 32; r += 8) t[r][tx] = Ws[(size_t)(k0 + r) * N + n0 + tx];
    __syncthreads();
#pragma unroll
    for (int r = ty; r < 32; r += 8) {
        float v = t[tx][r];
        size_t o = (size_t)(n0 + r) * K + k0 + tx;
        u16 hh = f2bf(v);
        Tho[o] = hh;
        Tlo[o] = f2bf(v - bf2f(hh));
    }
}

// ------------------------ u16 transpose for V: qkv planes -> VT [b][512d][512s]
__global__ __launch_bounds__(256) void vtrans_kernel(
    const u16* __restrict__ Qh, const u16* __restrict__ Ql,
    u16* __restrict__ VTh, u16* __restrict__ VTl) {
    __shared__ u16 t[64][68];
    int s0 = blockIdx.x * 64, d0 = blockIdx.y * 64;
    int b = blockIdx.z & 15, plane = blockIdx.z >> 4;
    const u16* src = (plane ? Ql : Qh);
    u16* dst = (plane ? VTl : VTh);
    int tid = threadIdx.x;
    int rr = tid >> 4, c4 = (tid & 15) * 4;
#pragma unroll
    for (int i = 0; i < 4; ++i) {
        int r = rr + i * 16;
        const u16* p = src + (size_t)(b * SEQ + s0 + r) * 1536 + 1024 + d0 + c4;
        *(u16x4*)(&t[r][c4]) = *(const u16x4*)p;
    }
    __syncthreads();
#pragma unroll
    for (int i = 0; i < 4; ++i) {
        int r = rr + i * 16; // d-index within tile
        u16x4 v;
        v.x = t[c4 + 0][r]; v.y = t[c4 + 1][r]; v.z = t[c4 + 2][r]; v.w = t[c4 + 3][r];
        *(u16x4*)(dst + (size_t)b * SEQ * DMODEL + (size_t)(d0 + r) * SEQ + s0 + c4) = v;
    }
}

// ------------------------------------------------ elementwise fp32 -> (hi,lo)
__global__ void split_kernel(const float* __restrict__ X, u16* __restrict__ H,
                             u16* __restrict__ L, int n) {
    int i = blockIdx.x * 256 + threadIdx.x;
    if (i < n) {
        float v = X[i];
        u16 hh = f2bf(v);
        H[i] = hh;
        L[i] = f2bf(v - bf2f(hh));
    }
}

// ------------------------------------------------------------------ layernorm
__global__ __launch_bounds__(256) void ln_kernel(
    const float* __restrict__ X, float* __restrict__ Y,
    u16* __restrict__ Yh, u16* __restrict__ Yl,
    const float* __restrict__ g, const float* __restrict__ b) {
    int row  = blockIdx.x * 4 + (threadIdx.x >> 6);
    int lane = threadIdx.x & 63;
    const float* x = X + (size_t)row * DMODEL;
    float v[8];
    float s = 0.0f;
#pragma unroll
    for (int j = 0; j < 8; ++j) { v[j] = x[lane + j * 64]; s += v[j]; }
#pragma unroll
    for (int off = 32; off; off >>= 1) s += __shfl_xor(s, off);
    float mu  = s * (1.0f / DMODEL);
    float var = 0.0f;
#pragma unroll
    for (int j = 0; j < 8; ++j) { float d = v[j] - mu; var += d * d; }
#pragma unroll
    for (int off = 32; off; off >>= 1) var += __shfl_xor(var, off);
    float r = rsqrtf(var * (1.0f / DMODEL) + 1e-5f);
#pragma unroll
    for (int j = 0; j < 8; ++j) {
        int d = lane + j * 64;
        float y = (v[j] - mu) * r * g[d] + b[d];
        size_t o = (size_t)row * DMODEL + d;
        Y[o] = y;
        if (Yh) {
            u16 hh = f2bf(y);
            Yh[o] = hh;
            Yl[o] = f2bf(y - bf2f(hh));
        }
    }
}

// --------------------------------------------------------- bf16x3 MFMA GEMM
__global__ __launch_bounds__(256) void gemm3_kernel(
    const u16* __restrict__ Ah, const u16* __restrict__ Al,
    const u16* __restrict__ Bh, const u16* __restrict__ Bl,
    float* __restrict__ Cf, u16* __restrict__ Ch, u16* __restrict__ Cl,
    const float* __restrict__ bias, const float* __restrict__ res,
    const float* __restrict__ pos, int M, int N, int K, int gelu) {
    __shared__ __align__(16) u16 AsU[128 * 32];
    __shared__ __align__(16) u16 BsU[128 * 32];

    int tid  = threadIdx.x;
    int w    = tid >> 6, lane = tid & 63;
    int wr   = w >> 1, wc = w & 1;
    int quad = lane >> 4, l16 = lane & 15;
    int m0   = blockIdx.x * 128;
    int n0   = blockIdx.y * 128;

    f32x4 acc[4][4];
#pragma unroll
    for (int i = 0; i < 4; ++i)
#pragma unroll
        for (int j = 0; j < 4; ++j) acc[i][j] = (f32x4){0.f, 0.f, 0.f, 0.f};

    int off0 = tid * 16;
    int row0s = off0 >> 6, ke0 = (off0 & 63) >> 1;
    int off1 = 4096 + tid * 16;
    int row1s = off1 >> 6, ke1 = (off1 & 63) >> 1;

#pragma unroll
    for (int pass = 0; pass < 3; ++pass) {
        const u16* Ap = (pass == 1) ? Al : Ah;
        const u16* Bp = (pass == 2) ? Bl : Bh;
        const u16* Abase = Ap + (size_t)m0 * K;
        const u16* Bbase = Bp + (size_t)n0 * K;
        for (int ks = 0; ks < K; ks += 32) {
            __syncthreads();
            async16(&AsU[off0 >> 1], Abase + (size_t)row0s * K + ks + ke0);
            async16(&BsU[off0 >> 1], Bbase + (size_t)row0s * K + ks + ke0);
            async16(&AsU[off1 >> 1], Abase + (size_t)row1s * K + ks + ke1);
            async16(&BsU[off1 >> 1], Bbase + (size_t)row1s * K + ks + ke1);
            __syncthreads();
            short8 af[4], bf[4];
#pragma unroll
            for (int i = 0; i < 4; ++i)
                af[i] = *(const short8*)&AsU[(wr * 64 + i * 16 + l16) * 32 + quad * 8];
#pragma unroll
            for (int i = 0; i < 4; ++i)
                bf[i] = *(const short8*)&BsU[(wc * 64 + i * 16 + l16) * 32 + quad * 8];
#pragma unroll
            for (int i = 0; i < 4; ++i)
#pragma unroll
                for (int j = 0; j < 4; ++j)
                    acc[i][j] = __builtin_amdgcn_mfma_f32_16x16x32_bf16(af[i], bf[j], acc[i][j], 0, 0, 0);
        }
    }

    int mbase = m0 + wr * 64;
    int nbase = n0 + wc * 64;
#pragma unroll
    for (int mi = 0; mi < 4; ++mi)
#pragma unroll
        for (int ni = 0; ni < 4; ++ni) {
            f32x4 a = acc[mi][ni];
#pragma unroll
            for (int r = 0; r < 4; ++r) {
                int m = mbase + mi * 16 + quad * 4 + r;
                int n = nbase + ni * 16 + l16;
                float v = a[r];
                if (bias) v += bias[n];
                if (pos)  v += pos[(size_t)(m & (SEQ - 1)) * N + n];
                if (res)  v += res[(size_t)m * N + n];
                if (gelu) v = gelu_tanh(v);
                size_t o = (size_t)m * N + n;
                if (Cf) Cf[o] = v;
                if (Ch) {
                    u16 hh = f2bf(v);
                    Ch[o] = hh;
                    Cl[o] = f2bf(v - bf2f(hh));
                }
            }
        }
}

// ------------------------------------------------------------ fp32 GEMM (small)
__global__ __launch_bounds__(256) void gemm_kernel(
    const float* __restrict__ A, const float* __restrict__ Bm,
    float* __restrict__ C, const float* __restrict__ bias,
    int M, int N, int K) {
    __shared__ float As[16][68];
    __shared__ float Bs[16][64];
    int tid = threadIdx.x;
    int tx = tid & 15, ty = tid >> 4;
    int a_m = tid >> 2, a_k = (tid & 3) * 4;
    int b_k = tid >> 4, b_n = (tid & 15) * 4;
    const float* Arow = A + (size_t)(blockIdx.x * 64 + a_m) * K;
    const float* Bcol = Bm + (size_t)blockIdx.y * 64 + b_n;
    float acc[4][4] = {};
    for (int k0 = 0; k0 < K; k0 += 16) {
        float4 av = *(const float4*)(Arow + k0 + a_k);
        float4 bv = *(const float4*)(Bcol + (size_t)(k0 + b_k) * N);
        __syncthreads();
        As[a_k + 0][a_m] = av.x; As[a_k + 1][a_m] = av.y;
        As[a_k + 2][a_m] = av.z; As[a_k + 3][a_m] = av.w;
        *(float4*)(&Bs[b_k][b_n]) = bv;
        __syncthreads();
#pragma unroll
        for (int kk = 0; kk < 16; ++kk) {
            float4 a4 = *(const float4*)(&As[kk][ty * 4]);
            float4 b4 = *(const float4*)(&Bs[kk][tx * 4]);
            float ar[4] = {a4.x, a4.y, a4.z, a4.w};
            float br[4] = {b4.x, b4.y, b4.z, b4.w};
#pragma unroll
            for (int i = 0; i < 4; ++i)
#pragma unroll
                for (int j = 0; j < 4; ++j) acc[i][j] = fmaf(ar[i], br[j], acc[i][j]);
        }
    }
    int m0 = blockIdx.x * 64 + ty * 4;
    int n0 = blockIdx.y * 64 + tx * 4;
#pragma unroll
    for (int i = 0; i < 4; ++i) {
        float vv[4];
#pragma unroll
        for (int j = 0; j < 4; ++j) {
            float t = acc[i][j];
            if (bias) t += bias[n0 + j];
            vv[j] = t;
        }
        *(float4*)(C + (size_t)(m0 + i) * N + n0) = make_float4(vv[0], vv[1], vv[2], vv[3]);
    }
}

// ----------------------------------------------------------- MFMA attention
__global__ __launch_bounds__(256) void attn_mfma_kernel(
    const u16* __restrict__ QKh, const u16* __restrict__ QKl,
    const u16* __restrict__ VTh, const u16* __restrict__ VTl,
    u16* __restrict__ Oh, u16* __restrict__ Ol) {
    int qt = blockIdx.x & 31;
    int hh = (blockIdx.x >> 5) & 7;
    int bb = blockIdx.x >> 8;

    __shared__ __align__(16) unsigned char ldsbuf[16 * 544 * 2 * 2]; // 34816 B
    float* sc = (float*)ldsbuf;       // [16][512] fp32
    u16* Ph = (u16*)ldsbuf;           // [16][544]
    u16* Pl = Ph + 16 * 544;

    int tid = threadIdx.x;
    int w = tid >> 6, lane = tid & 63;
    int quad = lane >> 4, l16 = lane & 15;

    const u16* qrh = QKh + (size_t)(bb * SEQ + qt * 16 + l16) * 1536 + hh * 64 + quad * 8;
    const u16* qrl = QKl + (size_t)(bb * SEQ + qt * 16 + l16) * 1536 + hh * 64 + quad * 8;
    short8 Qh0 = *(const short8*)qrh;
    short8 Qh1 = *(const short8*)(qrh + 32);
    short8 Ql0 = *(const short8*)qrl;
    short8 Ql1 = *(const short8*)(qrl + 32);

    for (int kt = 0; kt < 8; ++kt) {
        int krow = bb * SEQ + kt * 64 + w * 16 + l16;
        const u16* krh = QKh + (size_t)krow * 1536 + 512 + hh * 64 + quad * 8;
        const u16* krl = QKl + (size_t)krow * 1536 + 512 + hh * 64 + quad * 8;
        short8 Kh0 = *(const short8*)krh;
        short8 Kh1 = *(const short8*)(krh + 32);
        short8 Kl0 = *(const short8*)krl;
        short8 Kl1 = *(const short8*)(krl + 32);
        f32x4 a = (f32x4){0.f, 0.f, 0.f, 0.f};
        a = __builtin_amdgcn_mfma_f32_16x16x32_bf16(Qh0, Kh0, a, 0, 0, 0);
        a = __builtin_amdgcn_mfma_f32_16x16x32_bf16(Qh1, Kh1, a, 0, 0, 0);
        a = __builtin_amdgcn_mfma_f32_16x16x32_bf16(Ql0, Kh0, a, 0, 0, 0);
        a = __builtin_amdgcn_mfma_f32_16x16x32_bf16(Ql1, Kh1, a, 0, 0, 0);
        a = __builtin_amdgcn_mfma_f32_16x16x32_bf16(Qh0, Kl0, a, 0, 0, 0);
        a = __builtin_amdgcn_mfma_f32_16x16x32_bf16(Qh1, Kl1, a, 0, 0, 0);
        int key = kt * 64 + w * 16 + l16;
#pragma unroll
        for (int r = 0; r < 4; ++r)
            sc[(quad * 4 + r) * 512 + key] = a[r] * 0.125f;
    }
    __syncthreads();

    float e[4][8];
#pragma unroll
    for (int rr = 0; rr < 4; ++rr) {
        int qi = w + rr * 4;
        float m = -1e30f;
#pragma unroll
        for (int j = 0; j < 8; ++j) { e[rr][j] = sc[qi * 512 + lane + j * 64]; m = fmaxf(m, e[rr][j]); }
#pragma unroll
        for (int off = 32; off; off >>= 1) m = fmaxf(m, __shfl_xor(m, off));
        float sum = 0.0f;
#pragma unroll
        for (int j = 0; j < 8; ++j) { e[rr][j] = __expf(e[rr][j] - m); sum += e[rr][j]; }
#pragma unroll
        for (int off = 32; off; off >>= 1) sum += __shfl_xor(sum, off);
        float inv = 1.0f / sum;
#pragma unroll
        for (int j = 0; j < 8; ++j) e[rr][j] *= inv;
    }
    __syncthreads();

#pragma unroll
    for (int rr = 0; rr < 4; ++rr) {
        int qi = w + rr * 4;
#pragma unroll
        for (int j = 0; j < 8; ++j) {
            float v = e[rr][j];
            u16 hv = f2bf(v);
            Ph[qi * 544 + lane + j * 64] = hv;
            Pl[qi * 544 + lane + j * 64] = f2bf(v - bf2f(hv));
        }
    }
    __syncthreads();

    const u16* vth = VTh + ((size_t)bb * SEQ + hh * 64 + w * 16 + l16) * SEQ + quad * 8;
    const u16* vtl = VTl + ((size_t)bb * SEQ + hh * 64 + w * 16 + l16) * SEQ + quad * 8;
    const u16* ph = Ph + l16 * 544 + quad * 8;
    const u16* pl = Pl + l16 * 544 + quad * 8;
    f32x4 acc0 = (f32x4){0.f, 0.f, 0.f, 0.f};
    f32x4 acc1 = (f32x4){0.f, 0.f, 0.f, 0.f};
#pragma unroll
    for (int ks = 0; ks < 512; ks += 64) {
        short8 P0h = *(const short8*)(ph + ks);
        short8 P0l = *(const short8*)(pl + ks);
        short8 V0h = *(const short8*)(vth + ks);
        short8 V0l = *(const short8*)(vtl + ks);
        short8 P1h = *(const short8*)(ph + ks + 32);
        short8 P1l = *(const short8*)(pl + ks + 32);
        short8 V1h = *(const short8*)(vth + ks + 32);
        short8 V1l = *(const short8*)(vtl + ks + 32);
        acc0 = __builtin_amdgcn_mfma_f32_16x16x32_bf16(P0h, V0h, acc0, 0, 0, 0);
        acc1 = __builtin_amdgcn_mfma_f32_16x16x32_bf16(P1h, V1h, acc1, 0, 0, 0);
        acc0 = __builtin_amdgcn_mfma_f32_16x16x32_bf16(P0l, V0h, acc0, 0, 0, 0);
        acc1 = __builtin_amdgcn_mfma_f32_16x16x32_bf16(P1l, V1h, acc1, 0, 0, 0);
        acc0 = __builtin_amdgcn_mfma_f32_16x16x32_bf16(P0h, V0l, acc0, 0, 0, 0);
        acc1 = __builtin_amdgcn_mfma_f32_16x16x32_bf16(P1h, V1l, acc1, 0, 0, 0);
    }
    f32x4 o = acc0 + acc1;
#pragma unroll
    for (int r = 0; r < 4; ++r) {
        int q = quad * 4 + r;
        size_t off = (size_t)(bb * SEQ + qt * 16 + q) * DMODEL + hh * 64 + w * 16 + l16;
        u16 hv = f2bf(o[r]);
        Oh[off] = hv;
        Ol[off] = f2bf(o[r] - bf2f(hv));
    }
}

// ----------------------------------------------------------------- MFMA VQ
// block = 16 z-rows, 4 waves; wave w scans codes [w*2048, (w+1)*2048).
// Z rows = A frags (registers), codebook split planes [code][64] = B frags.
// score = |c|^2 - 2*(z.c) via 6 MFMA per 16-code tile (bf16x3 split).
__global__ __launch_bounds__(256) void vq3_kernel(
    const float* __restrict__ Z, const u16* __restrict__ Zh, const u16* __restrict__ Zl,
    const u16* __restrict__ CBh, const u16* __restrict__ CBl,
    const float* __restrict__ CB, const float* __restrict__ CBN,
    float* __restrict__ out) {
    __shared__ float sbest[4][16];
    __shared__ int sidx[4][16];
    __shared__ int ibest[16];
    __shared__ float psum[4][64];
    __shared__ float cl4[4];

    int tid = threadIdx.x;
    int w = tid >> 6, lane = tid & 63;
    int quad = lane >> 4, l16 = lane & 15;
    int row0 = blockIdx.x * 16;

    // A frags: lane l16 = z-row, quad*8+j = dim
    const u16* zph = Zh + (size_t)(row0 + l16) * CBD + quad * 8;
    const u16* zpl = Zl + (size_t)(row0 + l16) * CBD + quad * 8;
    short8 Z0h = *(const short8*)zph;
    short8 Z1h = *(const short8*)(zph + 32);
    short8 Z0l = *(const short8*)zpl;
    short8 Z1l = *(const short8*)(zpl + 32);

    float best[4] = {3.4e38f, 3.4e38f, 3.4e38f, 3.4e38f};
    int bidx[4] = {0, 0, 0, 0};

    int cbase = w * (CBS / 4);
#pragma unroll 2
    for (int t = 0; t < CBS / 4; t += 16) {
        int code = cbase + t + l16;
        const u16* cph = CBh + (size_t)code * CBD + quad * 8;
        const u16* cpl = CBl + (size_t)code * CBD + quad * 8;
        short8 C0h = *(const short8*)cph;
        short8 C1h = *(const short8*)(cph + 32);
        short8 C0l = *(const short8*)cpl;
        short8 C1l = *(const short8*)(cpl + 32);
        float cn = CBN[code];
        f32x4 a = (f32x4){0.f, 0.f, 0.f, 0.f};
        a = __builtin_amdgcn_mfma_f32_16x16x32_bf16(Z0h, C0h, a, 0, 0, 0);
        a = __builtin_amdgcn_mfma_f32_16x16x32_bf16(Z1h, C1h, a, 0, 0, 0);
        a = __builtin_amdgcn_mfma_f32_16x16x32_bf16(Z0l, C0h, a, 0, 0, 0);
        a = __builtin_amdgcn_mfma_f32_16x16x32_bf16(Z1l, C1h, a, 0, 0, 0);
        a = __builtin_amdgcn_mfma_f32_16x16x32_bf16(Z0h, C0l, a, 0, 0, 0);
        a = __builtin_amdgcn_mfma_f32_16x16x32_bf16(Z1h, C1l, a, 0, 0, 0);
        // C layout: col(l16)=code, row(quad*4+r)=z-row
#pragma unroll
        for (int r = 0; r < 4; ++r) {
            float s = cn - 2.0f * a[r];
            if (s < best[r]) { best[r] = s; bidx[r] = code; }
        }
    }
    // reduce across the 16 lanes of each quad group (xor bits 0..3)
#pragma unroll
    for (int off = 8; off; off >>= 1) {
#pragma unroll
        for (int r = 0; r < 4; ++r) {
            float ov = __shfl_xor(best[r], off);
            int oi = __shfl_xor(bidx[r], off);
            if (ov < best[r] || (ov == best[r] && oi < bidx[r])) { best[r] = ov; bidx[r] = oi; }
        }
    }
    if (l16 == 0) {
#pragma unroll
        for (int r = 0; r < 4; ++r) {
            sbest[w][quad * 4 + r] = best[r];
            sidx[w][quad * 4 + r] = bidx[r];
        }
    }
    __syncthreads();
    if (tid < 16) {
        float bv = sbest[0][tid];
        int bi = sidx[0][tid];
#pragma unroll
        for (int ww = 1; ww < 4; ++ww) {
            float ov = sbest[ww][tid];
            int oi = sidx[ww][tid];
            if (ov < bv || (ov == bv && oi < bi)) { bv = ov; bi = oi; }
        }
        ibest[tid] = bi;
    }
    __syncthreads();

    // epilogue: per-batch sums + commit loss (fp32 inputs)
    int d2 = lane;
    float qacc = 0.0f, closs = 0.0f;
#pragma unroll
    for (int j = 0; j < 4; ++j) {
        int r2 = w * 4 + j;
        int bi = ibest[r2];
        float q = CB[(size_t)bi * CBD + d2];
        float z = Z[(size_t)(row0 + r2) * CBD + d2];
        qacc += q;
        float df = q - z;
        closs += df * df;
    }
    psum[w][d2] = qacc;
#pragma unroll
    for (int off = 32; off; off >>= 1) closs += __shfl_xor(closs, off);
    if (d2 == 0) cl4[w] = closs;
    __syncthreads();
    if (tid < 64) {
        float t = psum[0][tid] + psum[1][tid] + psum[2][tid] + psum[3][tid];
        int b = row0 >> 9;
        atomicAdd(out + b * 64 + tid, t);
    }
    if (tid == 0)
        atomicAdd(out + 1024, (cl4[0] + cl4[1] + cl4[2] + cl4[3]) * (1.0f / (float)(MROWS * CBD)));
}

// -------------------------------------------------------------------- launch
extern "C" void kernel_launch(void* const* d_in, const int* in_sizes, int n_in,
                              void* d_out, int out_size, void* d_ws, size_t ws_size,
                              hipStream_t stream) {
    const float* x    = (const float*)d_in[0];
    const float* w_in = (const float*)d_in[1];
    const float* b_in = (const float*)d_in[2];
    const float* pos  = (const float*)d_in[3];
    const float* ln1g = (const float*)d_in[4];
    const float* ln1b = (const float*)d_in[5];
    const float* wq   = (const float*)d_in[6];
    const float* wk   = (const float*)d_in[7];
    const float* wv   = (const float*)d_in[8];
    const float* wo   = (const float*)d_in[9];
    const float* ln2g = (const float*)d_in[10];
    const float* ln2b = (const float*)d_in[11];
    const float* ffw1 = (const float*)d_in[12];
    const float* ffb1 = (const float*)d_in[13];
    const float* ffw2 = (const float*)d_in[14];
    const float* ffb2 = (const float*)d_in[15];
    const float* lnfg = (const float*)d_in[16];
    const float* lnfb = (const float*)d_in[17];
    const float* wout = (const float*)d_in[18];
    const float* bout = (const float*)d_in[19];
    const float* cb   = (const float*)d_in[20];
    float* out = (float*)d_out;

    const size_t MD  = (size_t)MROWS * DMODEL;   // 4,194,304
    const size_t MQ  = (size_t)MROWS * 1536;     // 12,582,912
    const size_t MF  = (size_t)MROWS * DFF;      // 16,777,216

    float* ws   = (float*)d_ws;
    float* h    = ws;
    float* t0   = h + MD;
    float* big  = t0 + MD;                   // MF floats (aliased region)
    float* zb   = big + MF;
    float* cbn  = zb + (size_t)MROWS * CBD;
    // codebook split planes live in the old cbT slot (0.5M floats = 2x524288 u16)
    u16* cbh    = (u16*)(cbn + CBS);
    u16* cbl    = cbh + (size_t)CBS * CBD;
    u16* t0h    = (u16*)(cbh + 2 * (size_t)CBS * CBD);
    u16* t0l    = t0h + MD;
    u16* wb     = t0l + MD;

    // big aliases
    u16* qkvh = (u16*)big;
    u16* qkvl = qkvh + MQ;
    u16* obh  = qkvl + MQ;
    u16* obl  = obh + MD;
    u16* xh   = obh;
    u16* xl   = obl;
    u16* fmh  = (u16*)big;
    u16* fml  = fmh + MF;
    u16* zbh  = (u16*)big;        // VQ phase: big region is dead
    u16* zbl  = zbh + (size_t)MROWS * CBD;

    const size_t S_WIN  = (size_t)DMODEL * DMODEL;
    const size_t S_QKV  = (size_t)1536 * DMODEL * NDEPTH;
    const size_t S_WO   = S_WIN * NDEPTH;
    const size_t S_FF1  = (size_t)DFF * DMODEL * NDEPTH;
    const size_t S_FF2  = S_FF1;
    u16* winT_h = wb;
    u16* winT_l = winT_h + S_WIN;
    u16* qkvT_h = winT_l + S_WIN;
    u16* qkvT_l = qkvT_h + S_QKV;
    u16* woT_h  = qkvT_l + S_QKV;
    u16* woT_l  = woT_h + S_WO;
    u16* ff1T_h = woT_l + S_WO;
    u16* ff1T_l = ff1T_h + S_FF1;
    u16* ff2T_h = ff1T_l + S_FF1;
    u16* ff2T_l = ff2T_h + S_FF2;
    u16* VTh = ff2T_l + S_FF2;
    u16* VTl = VTh + (size_t)BATCH * SEQ * DMODEL;

    dim3 blk(256);

    zero_kernel<<<dim3((out_size + 255) / 256), blk, 0, stream>>>(out, out_size);
    cbn_kernel<<<dim3(CBS / 256), blk, 0, stream>>>(cb, cbn);
    split_kernel<<<dim3((int)(CBS * CBD / 256)), blk, 0, stream>>>(cb, cbh, cbl, CBS * CBD);

    wtrans_kernel<<<dim3(16, 16, 1), blk, 0, stream>>>(w_in, winT_h, winT_l, DMODEL, DMODEL, 0, 0);
    wtrans_kernel<<<dim3(16, 16, NDEPTH), blk, 0, stream>>>(
        wq, qkvT_h, qkvT_l, DMODEL, DMODEL, (long)DMODEL * DMODEL, (long)1536 * DMODEL);
    wtrans_kernel<<<dim3(16, 16, NDEPTH), blk, 0, stream>>>(
        wk, qkvT_h + (size_t)512 * DMODEL, qkvT_l + (size_t)512 * DMODEL,
        DMODEL, DMODEL, (long)DMODEL * DMODEL, (long)1536 * DMODEL);
    wtrans_kernel<<<dim3(16, 16, NDEPTH), blk, 0, stream>>>(
        wv, qkvT_h + (size_t)1024 * DMODEL, qkvT_l + (size_t)1024 * DMODEL,
        DMODEL, DMODEL, (long)DMODEL * DMODEL, (long)1536 * DMODEL);
    wtrans_kernel<<<dim3(16, 16, NDEPTH), blk, 0, stream>>>(
        wo, woT_h, woT_l, DMODEL, DMODEL, (long)DMODEL * DMODEL, (long)DMODEL * DMODEL);
    wtrans_kernel<<<dim3(DFF / 32, 16, NDEPTH), blk, 0, stream>>>(
        ffw1, ff1T_h, ff1T_l, DMODEL, DFF, (long)DMODEL * DFF, (long)DFF * DMODEL);
    wtrans_kernel<<<dim3(16, DFF / 32, NDEPTH), blk, 0, stream>>>(
        ffw2, ff2T_h, ff2T_l, DFF, DMODEL, (long)DFF * DMODEL, (long)DMODEL * DFF);

    split_kernel<<<dim3((int)(MD / 256)), blk, 0, stream>>>(x, xh, xl, (int)MD);

    gemm3_kernel<<<dim3(MROWS / 128, DMODEL / 128), blk, 0, stream>>>(
        xh, xl, winT_h, winT_l, h, nullptr, nullptr, b_in, nullptr, pos,
        MROWS, DMODEL, DMODEL, 0);

    for (int l = 0; l < NDEPTH; ++l) {
        ln_kernel<<<dim3(MROWS / 4), blk, 0, stream>>>(
            h, t0, t0h, t0l, ln1g + l * DMODEL, ln1b + l * DMODEL);
        gemm3_kernel<<<dim3(MROWS / 128, 1536 / 128), blk, 0, stream>>>(
            t0h, t0l, qkvT_h + (size_t)l * 1536 * DMODEL, qkvT_l + (size_t)l * 1536 * DMODEL,
            nullptr, qkvh, qkvl, nullptr, nullptr, nullptr, MROWS, 1536, DMODEL, 0);
        vtrans_kernel<<<dim3(8, 8, 32), blk, 0, stream>>>(qkvh, qkvl, VTh, VTl);
        attn_mfma_kernel<<<dim3(BATCH * NHEADS * (SEQ / 16)), blk, 0, stream>>>(
            qkvh, qkvl, VTh, VTl, obh, obl);
        gemm3_kernel<<<dim3(MROWS / 128, DMODEL / 128), blk, 0, stream>>>(
            obh, obl, woT_h + (size_t)l * S_WIN, woT_l + (size_t)l * S_WIN,
            h, nullptr, nullptr, nullptr, h, nullptr, MROWS, DMODEL, DMODEL, 0);

        ln_kernel<<<dim3(MROWS / 4), blk, 0, stream>>>(
            h, t0, t0h, t0l, ln2g + l * DMODEL, ln2b + l * DMODEL);
        gemm3_kernel<<<dim3(MROWS / 128, DFF / 128), blk, 0, stream>>>(
            t0h, t0l, ff1T_h + (size_t)l * DFF * DMODEL, ff1T_l + (size_t)l * DFF * DMODEL,
            nullptr, fmh, fml, ffb1 + l * DFF, nullptr, nullptr, MROWS, DFF, DMODEL, 1);
        gemm3_kernel<<<dim3(MROWS / 128, DMODEL / 128), blk, 0, stream>>>(
            fmh, fml, ff2T_h + (size_t)l * DFF * DMODEL, ff2T_l + (size_t)l * DFF * DMODEL,
            h, nullptr, nullptr, ffb2 + l * DMODEL, h, nullptr, MROWS, DMODEL, DFF, 0);
    }

    ln_kernel<<<dim3(MROWS / 4), blk, 0, stream>>>(h, t0, nullptr, nullptr, lnfg, lnfb);
    gemm_kernel<<<dim3(MROWS / 64, 1), blk, 0, stream>>>(t0, wout, zb, bout, MROWS, CBD, DMODEL);
    // split z for MFMA VQ (big region is dead now)
    split_kernel<<<dim3((int)((size_t)MROWS * CBD / 256)), blk, 0, stream>>>(
        zb, zbh, zbl, MROWS * CBD);
    vq3_kernel<<<dim3(MROWS / 16), blk, 0, stream>>>(zb, zbh, zbl, cbh, cbl, cb, cbn, out);
}

// Round 5
// 2111.172 us; speedup vs baseline: 2.7056x; 1.1503x over previous
//
#include <hip/hip_runtime.h>
#include <cmath>

#define BATCH 16
#define SEQ 512
#define DMODEL 512
#define NDEPTH 4
#define NHEADS 8
#define DHEAD 64
#define DFF 2048
#define CBD 64
#define CBS 8192
#define MROWS (BATCH * SEQ) // 8192

typedef unsigned short u16;
typedef __attribute__((ext_vector_type(8))) short short8; // 8 bf16 = 4 VGPRs (MFMA A/B frag)
typedef __attribute__((ext_vector_type(4))) float f32x4;  // MFMA C/D frag
typedef __attribute__((ext_vector_type(4))) unsigned short u16x4;

// ---------------------------------------------------------------- bf16 helpers
__device__ __forceinline__ u16 f2bf(float f) {
    unsigned u = __float_as_uint(f);
    u += 0x7fff + ((u >> 16) & 1); // RNE
    return (u16)(u >> 16);
}
__device__ __forceinline__ float bf2f(u16 h) {
    return __uint_as_float(((unsigned)h) << 16);
}

// async global->LDS 16B: LDS dest must be wave-uniform base + lane*16
__device__ __forceinline__ void async16(u16* lds, const u16* g) {
    __builtin_amdgcn_global_load_lds(
        (const __attribute__((address_space(1))) unsigned int*)g,
        (__attribute__((address_space(3))) unsigned int*)lds, 16, 0, 0);
}

__device__ __forceinline__ float gelu_tanh(float u) {
    return 0.5f * u * (1.0f + tanhf(0.7978845608028654f * (u + 0.044715f * u * u * u)));
}

// ---------------------------------------------------------------- zero output
__global__ void zero_kernel(float* __restrict__ p, int n) {
    int i = blockIdx.x * 256 + threadIdx.x;
    if (i < n) p[i] = 0.0f;
}

// ------------------------------------------------------------- codebook norms
__global__ void cbn_kernel(const float* __restrict__ cb, float* __restrict__ cbn) {
    int c = blockIdx.x * 256 + threadIdx.x;
    if (c >= CBS) return;
    const float* row = cb + (size_t)c * CBD;
    float s = 0.0f;
#pragma unroll
    for (int d = 0; d < CBD; ++d) s += row[d] * row[d];
    cbn[c] = s;
}

// ------------------------- weight transpose + split: W [z][K][N] -> T [z][N][K]
__global__ __launch_bounds__(256) void wtrans_kernel(
    const float* __restrict__ W, u16* __restrict__ Th, u16* __restrict__ Tl,
    int K, int N, long inLS, long outLS) {
    __shared__ float t[32][33];
    const float* Ws = W + (size_t)blockIdx.z * inLS;
    u16* Tho = Th + (size_t)blockIdx.z * outLS;
    u16* Tlo = Tl + (size_t)blockIdx.z * outLS;
    int n0 = blockIdx.x * 32, k0 = blockIdx.y * 32;
    int tx = threadIdx.x & 31, ty = threadIdx.x >> 5;
#pragma unroll
    for (int r = ty; r < 32; r += 8) t[r][tx] = Ws[(size_t)(k0 + r) * N + n0 + tx];
    __syncthreads();
#pragma unroll
    for (int r = ty; r < 32; r += 8) {
        float v = t[tx][r];
        size_t o = (size_t)(n0 + r) * K + k0 + tx;
        u16 hh = f2bf(v);
        Tho[o] = hh;
        Tlo[o] = f2bf(v - bf2f(hh));
    }
}

// ------------------------ u16 transpose for V: qkv planes -> VT [b][512d][512s]
__global__ __launch_bounds__(256) void vtrans_kernel(
    const u16* __restrict__ Qh, const u16* __restrict__ Ql,
    u16* __restrict__ VTh, u16* __restrict__ VTl) {
    __shared__ u16 t[64][68];
    int s0 = blockIdx.x * 64, d0 = blockIdx.y * 64;
    int b = blockIdx.z & 15, plane = blockIdx.z >> 4;
    const u16* src = (plane ? Ql : Qh);
    u16* dst = (plane ? VTl : VTh);
    int tid = threadIdx.x;
    int rr = tid >> 4, c4 = (tid & 15) * 4;
#pragma unroll
    for (int i = 0; i < 4; ++i) {
        int r = rr + i * 16;
        const u16* p = src + (size_t)(b * SEQ + s0 + r) * 1536 + 1024 + d0 + c4;
        *(u16x4*)(&t[r][c4]) = *(const u16x4*)p;
    }
    __syncthreads();
#pragma unroll
    for (int i = 0; i < 4; ++i) {
        int r = rr + i * 16; // d-index within tile
        u16x4 v;
        v.x = t[c4 + 0][r]; v.y = t[c4 + 1][r]; v.z = t[c4 + 2][r]; v.w = t[c4 + 3][r];
        *(u16x4*)(dst + (size_t)b * SEQ * DMODEL + (size_t)(d0 + r) * SEQ + s0 + c4) = v;
    }
}

// ------------------------------------------------ elementwise fp32 -> (hi,lo)
__global__ void split_kernel(const float* __restrict__ X, u16* __restrict__ H,
                             u16* __restrict__ L, int n) {
    int i = blockIdx.x * 256 + threadIdx.x;
    if (i < n) {
        float v = X[i];
        u16 hh = f2bf(v);
        H[i] = hh;
        L[i] = f2bf(v - bf2f(hh));
    }
}

// ---------------------------------------- layernorm (+split-K reduce folding)
// x = X + C0 + C1 + bias2 + pos2 (any may be null); Xout=x; then LN -> Y/Yh/Yl
__global__ __launch_bounds__(256) void ln_kernel(
    const float* __restrict__ X,
    const float* __restrict__ C0, const float* __restrict__ C1,
    const float* __restrict__ bias2, const float* __restrict__ pos2,
    float* __restrict__ Xout,
    float* __restrict__ Y, u16* __restrict__ Yh, u16* __restrict__ Yl,
    const float* __restrict__ g, const float* __restrict__ b) {
    int row  = blockIdx.x * 4 + (threadIdx.x >> 6);
    int lane = threadIdx.x & 63;
    float v[8];
    float s = 0.0f;
#pragma unroll
    for (int j = 0; j < 8; ++j) {
        int d = lane + j * 64;
        size_t o = (size_t)row * DMODEL + d;
        float t = X ? X[o] : 0.0f;
        if (C0)    t += C0[o] + C1[o];
        if (bias2) t += bias2[d];
        if (pos2)  t += pos2[(size_t)(row & (SEQ - 1)) * DMODEL + d];
        v[j] = t;
        if (Xout) Xout[o] = t;
        s += t;
    }
#pragma unroll
    for (int off = 32; off; off >>= 1) s += __shfl_xor(s, off);
    float mu  = s * (1.0f / DMODEL);
    float var = 0.0f;
#pragma unroll
    for (int j = 0; j < 8; ++j) { float d = v[j] - mu; var += d * d; }
#pragma unroll
    for (int off = 32; off; off >>= 1) var += __shfl_xor(var, off);
    float r = rsqrtf(var * (1.0f / DMODEL) + 1e-5f);
#pragma unroll
    for (int j = 0; j < 8; ++j) {
        int d = lane + j * 64;
        float y = (v[j] - mu) * r * g[d] + b[d];
        size_t o = (size_t)row * DMODEL + d;
        if (Y) Y[o] = y;
        if (Yh) {
            u16 hh = f2bf(y);
            Yh[o] = hh;
            Yl[o] = f2bf(y - bf2f(hh));
        }
    }
}

// --------------------------------------------------------- bf16x3 MFMA GEMM
// kslice>0: block handles K range [blockIdx.z*kslice, +kslice), stores raw fp32
// partial tile to Cs0/Cs1 (reduction folded into the next ln_kernel).
__global__ __launch_bounds__(256) void gemm3_kernel(
    const u16* __restrict__ Ah, const u16* __restrict__ Al,
    const u16* __restrict__ Bh, const u16* __restrict__ Bl,
    float* __restrict__ Cf, u16* __restrict__ Ch, u16* __restrict__ Cl,
    const float* __restrict__ bias, const float* __restrict__ res,
    const float* __restrict__ pos, int M, int N, int K, int gelu,
    float* __restrict__ Cs0, float* __restrict__ Cs1, int kslice) {
    __shared__ __align__(16) u16 AsU[128 * 32];
    __shared__ __align__(16) u16 BsU[128 * 32];

    int tid  = threadIdx.x;
    int w    = tid >> 6, lane = tid & 63;
    int wr   = w >> 1, wc = w & 1;
    int quad = lane >> 4, l16 = lane & 15;
    int m0   = blockIdx.x * 128;
    int n0   = blockIdx.y * 128;
    int ksA  = (kslice > 0) ? blockIdx.z * kslice : 0;
    int ksB  = (kslice > 0) ? ksA + kslice : K;

    f32x4 acc[4][4];
#pragma unroll
    for (int i = 0; i < 4; ++i)
#pragma unroll
        for (int j = 0; j < 4; ++j) acc[i][j] = (f32x4){0.f, 0.f, 0.f, 0.f};

    int off0 = tid * 16;
    int row0s = off0 >> 6, ke0 = (off0 & 63) >> 1;
    int off1 = 4096 + tid * 16;
    int row1s = off1 >> 6, ke1 = (off1 & 63) >> 1;

#pragma unroll
    for (int pass = 0; pass < 3; ++pass) {
        const u16* Ap = (pass == 1) ? Al : Ah;
        const u16* Bp = (pass == 2) ? Bl : Bh;
        const u16* Abase = Ap + (size_t)m0 * K;
        const u16* Bbase = Bp + (size_t)n0 * K;
        for (int ks = ksA; ks < ksB; ks += 32) {
            __syncthreads();
            async16(&AsU[off0 >> 1], Abase + (size_t)row0s * K + ks + ke0);
            async16(&BsU[off0 >> 1], Bbase + (size_t)row0s * K + ks + ke0);
            async16(&AsU[off1 >> 1], Abase + (size_t)row1s * K + ks + ke1);
            async16(&BsU[off1 >> 1], Bbase + (size_t)row1s * K + ks + ke1);
            __syncthreads();
            short8 af[4], bf[4];
#pragma unroll
            for (int i = 0; i < 4; ++i)
                af[i] = *(const short8*)&AsU[(wr * 64 + i * 16 + l16) * 32 + quad * 8];
#pragma unroll
            for (int i = 0; i < 4; ++i)
                bf[i] = *(const short8*)&BsU[(wc * 64 + i * 16 + l16) * 32 + quad * 8];
#pragma unroll
            for (int i = 0; i < 4; ++i)
#pragma unroll
                for (int j = 0; j < 4; ++j)
                    acc[i][j] = __builtin_amdgcn_mfma_f32_16x16x32_bf16(af[i], bf[j], acc[i][j], 0, 0, 0);
        }
    }

    float* Cspl = (kslice > 0) ? (blockIdx.z ? Cs1 : Cs0) : nullptr;
    int mbase = m0 + wr * 64;
    int nbase = n0 + wc * 64;
#pragma unroll
    for (int mi = 0; mi < 4; ++mi)
#pragma unroll
        for (int ni = 0; ni < 4; ++ni) {
            f32x4 a = acc[mi][ni];
#pragma unroll
            for (int r = 0; r < 4; ++r) {
                int m = mbase + mi * 16 + quad * 4 + r;
                int n = nbase + ni * 16 + l16;
                float v = a[r];
                size_t o = (size_t)m * N + n;
                if (Cspl) { Cspl[o] = v; continue; }
                if (bias) v += bias[n];
                if (pos)  v += pos[(size_t)(m & (SEQ - 1)) * N + n];
                if (res)  v += res[(size_t)m * N + n];
                if (gelu) v = gelu_tanh(v);
                if (Cf) Cf[o] = v;
                if (Ch) {
                    u16 hh = f2bf(v);
                    Ch[o] = hh;
                    Cl[o] = f2bf(v - bf2f(hh));
                }
            }
        }
}

// ------------------------------------------------------------ fp32 GEMM (small)
__global__ __launch_bounds__(256) void gemm_kernel(
    const float* __restrict__ A, const float* __restrict__ Bm,
    float* __restrict__ C, const float* __restrict__ bias,
    int M, int N, int K) {
    __shared__ float As[16][68];
    __shared__ float Bs[16][64];
    int tid = threadIdx.x;
    int tx = tid & 15, ty = tid >> 4;
    int a_m = tid >> 2, a_k = (tid & 3) * 4;
    int b_k = tid >> 4, b_n = (tid & 15) * 4;
    const float* Arow = A + (size_t)(blockIdx.x * 64 + a_m) * K;
    const float* Bcol = Bm + (size_t)blockIdx.y * 64 + b_n;
    float acc[4][4] = {};
    for (int k0 = 0; k0 < K; k0 += 16) {
        float4 av = *(const float4*)(Arow + k0 + a_k);
        float4 bv = *(const float4*)(Bcol + (size_t)(k0 + b_k) * N);
        __syncthreads();
        As[a_k + 0][a_m] = av.x; As[a_k + 1][a_m] = av.y;
        As[a_k + 2][a_m] = av.z; As[a_k + 3][a_m] = av.w;
        *(float4*)(&Bs[b_k][b_n]) = bv;
        __syncthreads();
#pragma unroll
        for (int kk = 0; kk < 16; ++kk) {
            float4 a4 = *(const float4*)(&As[kk][ty * 4]);
            float4 b4 = *(const float4*)(&Bs[kk][tx * 4]);
            float ar[4] = {a4.x, a4.y, a4.z, a4.w};
            float br[4] = {b4.x, b4.y, b4.z, b4.w};
#pragma unroll
            for (int i = 0; i < 4; ++i)
#pragma unroll
                for (int j = 0; j < 4; ++j) acc[i][j] = fmaf(ar[i], br[j], acc[i][j]);
        }
    }
    int m0 = blockIdx.x * 64 + ty * 4;
    int n0 = blockIdx.y * 64 + tx * 4;
#pragma unroll
    for (int i = 0; i < 4; ++i) {
        float vv[4];
#pragma unroll
        for (int j = 0; j < 4; ++j) {
            float t = acc[i][j];
            if (bias) t += bias[n0 + j];
            vv[j] = t;
        }
        *(float4*)(C + (size_t)(m0 + i) * N + n0) = make_float4(vv[0], vv[1], vv[2], vv[3]);
    }
}

// ----------------------------------------------------------- MFMA attention
__global__ __launch_bounds__(256) void attn_mfma_kernel(
    const u16* __restrict__ QKh, const u16* __restrict__ QKl,
    const u16* __restrict__ VTh, const u16* __restrict__ VTl,
    u16* __restrict__ Oh, u16* __restrict__ Ol) {
    int qt = blockIdx.x & 31;
    int hh = (blockIdx.x >> 5) & 7;
    int bb = blockIdx.x >> 8;

    __shared__ __align__(16) unsigned char ldsbuf[16 * 544 * 2 * 2]; // 34816 B
    float* sc = (float*)ldsbuf;       // [16][512] fp32
    u16* Ph = (u16*)ldsbuf;           // [16][544]
    u16* Pl = Ph + 16 * 544;

    int tid = threadIdx.x;
    int w = tid >> 6, lane = tid & 63;
    int quad = lane >> 4, l16 = lane & 15;

    const u16* qrh = QKh + (size_t)(bb * SEQ + qt * 16 + l16) * 1536 + hh * 64 + quad * 8;
    const u16* qrl = QKl + (size_t)(bb * SEQ + qt * 16 + l16) * 1536 + hh * 64 + quad * 8;
    short8 Qh0 = *(const short8*)qrh;
    short8 Qh1 = *(const short8*)(qrh + 32);
    short8 Ql0 = *(const short8*)qrl;
    short8 Ql1 = *(const short8*)(qrl + 32);

    for (int kt = 0; kt < 8; ++kt) {
        int krow = bb * SEQ + kt * 64 + w * 16 + l16;
        const u16* krh = QKh + (size_t)krow * 1536 + 512 + hh * 64 + quad * 8;
        const u16* krl = QKl + (size_t)krow * 1536 + 512 + hh * 64 + quad * 8;
        short8 Kh0 = *(const short8*)krh;
        short8 Kh1 = *(const short8*)(krh + 32);
        short8 Kl0 = *(const short8*)krl;
        short8 Kl1 = *(const short8*)(krl + 32);
        f32x4 a = (f32x4){0.f, 0.f, 0.f, 0.f};
        a = __builtin_amdgcn_mfma_f32_16x16x32_bf16(Qh0, Kh0, a, 0, 0, 0);
        a = __builtin_amdgcn_mfma_f32_16x16x32_bf16(Qh1, Kh1, a, 0, 0, 0);
        a = __builtin_amdgcn_mfma_f32_16x16x32_bf16(Ql0, Kh0, a, 0, 0, 0);
        a = __builtin_amdgcn_mfma_f32_16x16x32_bf16(Ql1, Kh1, a, 0, 0, 0);
        a = __builtin_amdgcn_mfma_f32_16x16x32_bf16(Qh0, Kl0, a, 0, 0, 0);
        a = __builtin_amdgcn_mfma_f32_16x16x32_bf16(Qh1, Kl1, a, 0, 0, 0);
        int key = kt * 64 + w * 16 + l16;
#pragma unroll
        for (int r = 0; r < 4; ++r)
            sc[(quad * 4 + r) * 512 + key] = a[r] * 0.125f;
    }
    __syncthreads();

    float e[4][8];
#pragma unroll
    for (int rr = 0; rr < 4; ++rr) {
        int qi = w + rr * 4;
        float m = -1e30f;
#pragma unroll
        for (int j = 0; j < 8; ++j) { e[rr][j] = sc[qi * 512 + lane + j * 64]; m = fmaxf(m, e[rr][j]); }
#pragma unroll
        for (int off = 32; off; off >>= 1) m = fmaxf(m, __shfl_xor(m, off));
        float sum = 0.0f;
#pragma unroll
        for (int j = 0; j < 8; ++j) { e[rr][j] = __expf(e[rr][j] - m); sum += e[rr][j]; }
#pragma unroll
        for (int off = 32; off; off >>= 1) sum += __shfl_xor(sum, off);
        float inv = 1.0f / sum;
#pragma unroll
        for (int j = 0; j < 8; ++j) e[rr][j] *= inv;
    }
    __syncthreads();

#pragma unroll
    for (int rr = 0; rr < 4; ++rr) {
        int qi = w + rr * 4;
#pragma unroll
        for (int j = 0; j < 8; ++j) {
            float v = e[rr][j];
            u16 hv = f2bf(v);
            Ph[qi * 544 + lane + j * 64] = hv;
            Pl[qi * 544 + lane + j * 64] = f2bf(v - bf2f(hv));
        }
    }
    __syncthreads();

    const u16* vth = VTh + ((size_t)bb * SEQ + hh * 64 + w * 16 + l16) * SEQ + quad * 8;
    const u16* vtl = VTl + ((size_t)bb * SEQ + hh * 64 + w * 16 + l16) * SEQ + quad * 8;
    const u16* ph = Ph + l16 * 544 + quad * 8;
    const u16* pl = Pl + l16 * 544 + quad * 8;
    f32x4 acc0 = (f32x4){0.f, 0.f, 0.f, 0.f};
    f32x4 acc1 = (f32x4){0.f, 0.f, 0.f, 0.f};
#pragma unroll
    for (int ks = 0; ks < 512; ks += 64) {
        short8 P0h = *(const short8*)(ph + ks);
        short8 P0l = *(const short8*)(pl + ks);
        short8 V0h = *(const short8*)(vth + ks);
        short8 V0l = *(const short8*)(vtl + ks);
        short8 P1h = *(const short8*)(ph + ks + 32);
        short8 P1l = *(const short8*)(pl + ks + 32);
        short8 V1h = *(const short8*)(vth + ks + 32);
        short8 V1l = *(const short8*)(vtl + ks + 32);
        acc0 = __builtin_amdgcn_mfma_f32_16x16x32_bf16(P0h, V0h, acc0, 0, 0, 0);
        acc1 = __builtin_amdgcn_mfma_f32_16x16x32_bf16(P1h, V1h, acc1, 0, 0, 0);
        acc0 = __builtin_amdgcn_mfma_f32_16x16x32_bf16(P0l, V0h, acc0, 0, 0, 0);
        acc1 = __builtin_amdgcn_mfma_f32_16x16x32_bf16(P1l, V1h, acc1, 0, 0, 0);
        acc0 = __builtin_amdgcn_mfma_f32_16x16x32_bf16(P0h, V0l, acc0, 0, 0, 0);
        acc1 = __builtin_amdgcn_mfma_f32_16x16x32_bf16(P1h, V1l, acc1, 0, 0, 0);
    }
    f32x4 o = acc0 + acc1;
#pragma unroll
    for (int r = 0; r < 4; ++r) {
        int q = quad * 4 + r;
        size_t off = (size_t)(bb * SEQ + qt * 16 + q) * DMODEL + hh * 64 + w * 16 + l16;
        u16 hv = f2bf(o[r]);
        Oh[off] = hv;
        Ol[off] = f2bf(o[r] - bf2f(hv));
    }
}

// ----------------------------------------------------------------- MFMA VQ
__global__ __launch_bounds__(256) void vq3_kernel(
    const float* __restrict__ Z, const u16* __restrict__ Zh, const u16* __restrict__ Zl,
    const u16* __restrict__ CBh, const u16* __restrict__ CBl,
    const float* __restrict__ CB, const float* __restrict__ CBN,
    float* __restrict__ out) {
    __shared__ float sbest[4][16];
    __shared__ int sidx[4][16];
    __shared__ int ibest[16];
    __shared__ float psum[4][64];
    __shared__ float cl4[4];

    int tid = threadIdx.x;
    int w = tid >> 6, lane = tid & 63;
    int quad = lane >> 4, l16 = lane & 15;
    int row0 = blockIdx.x * 16;

    const u16* zph = Zh + (size_t)(row0 + l16) * CBD + quad * 8;
    const u16* zpl = Zl + (size_t)(row0 + l16) * CBD + quad * 8;
    short8 Z0h = *(const short8*)zph;
    short8 Z1h = *(const short8*)(zph + 32);
    short8 Z0l = *(const short8*)zpl;
    short8 Z1l = *(const short8*)(zpl + 32);

    float best[4] = {3.4e38f, 3.4e38f, 3.4e38f, 3.4e38f};
    int bidx[4] = {0, 0, 0, 0};

    int cbase = w * (CBS / 4);
#pragma unroll 2
    for (int t = 0; t < CBS / 4; t += 16) {
        int code = cbase + t + l16;
        const u16* cph = CBh + (size_t)code * CBD + quad * 8;
        const u16* cpl = CBl + (size_t)code * CBD + quad * 8;
        short8 C0h = *(const short8*)cph;
        short8 C1h = *(const short8*)(cph + 32);
        short8 C0l = *(const short8*)cpl;
        short8 C1l = *(const short8*)(cpl + 32);
        float cn = CBN[code];
        f32x4 a = (f32x4){0.f, 0.f, 0.f, 0.f};
        a = __builtin_amdgcn_mfma_f32_16x16x32_bf16(Z0h, C0h, a, 0, 0, 0);
        a = __builtin_amdgcn_mfma_f32_16x16x32_bf16(Z1h, C1h, a, 0, 0, 0);
        a = __builtin_amdgcn_mfma_f32_16x16x32_bf16(Z0l, C0h, a, 0, 0, 0);
        a = __builtin_amdgcn_mfma_f32_16x16x32_bf16(Z1l, C1h, a, 0, 0, 0);
        a = __builtin_amdgcn_mfma_f32_16x16x32_bf16(Z0h, C0l, a, 0, 0, 0);
        a = __builtin_amdgcn_mfma_f32_16x16x32_bf16(Z1h, C1l, a, 0, 0, 0);
#pragma unroll
        for (int r = 0; r < 4; ++r) {
            float s = cn - 2.0f * a[r];
            if (s < best[r]) { best[r] = s; bidx[r] = code; }
        }
    }
#pragma unroll
    for (int off = 8; off; off >>= 1) {
#pragma unroll
        for (int r = 0; r < 4; ++r) {
            float ov = __shfl_xor(best[r], off);
            int oi = __shfl_xor(bidx[r], off);
            if (ov < best[r] || (ov == best[r] && oi < bidx[r])) { best[r] = ov; bidx[r] = oi; }
        }
    }
    if (l16 == 0) {
#pragma unroll
        for (int r = 0; r < 4; ++r) {
            sbest[w][quad * 4 + r] = best[r];
            sidx[w][quad * 4 + r] = bidx[r];
        }
    }
    __syncthreads();
    if (tid < 16) {
        float bv = sbest[0][tid];
        int bi = sidx[0][tid];
#pragma unroll
        for (int ww = 1; ww < 4; ++ww) {
            float ov = sbest[ww][tid];
            int oi = sidx[ww][tid];
            if (ov < bv || (ov == bv && oi < bi)) { bv = ov; bi = oi; }
        }
        ibest[tid] = bi;
    }
    __syncthreads();

    int d2 = lane;
    float qacc = 0.0f, closs = 0.0f;
#pragma unroll
    for (int j = 0; j < 4; ++j) {
        int r2 = w * 4 + j;
        int bi = ibest[r2];
        float q = CB[(size_t)bi * CBD + d2];
        float z = Z[(size_t)(row0 + r2) * CBD + d2];
        qacc += q;
        float df = q - z;
        closs += df * df;
    }
    psum[w][d2] = qacc;
#pragma unroll
    for (int off = 32; off; off >>= 1) closs += __shfl_xor(closs, off);
    if (d2 == 0) cl4[w] = closs;
    __syncthreads();
    if (tid < 64) {
        float t = psum[0][tid] + psum[1][tid] + psum[2][tid] + psum[3][tid];
        int b = row0 >> 9;
        atomicAdd(out + b * 64 + tid, t);
    }
    if (tid == 0)
        atomicAdd(out + 1024, (cl4[0] + cl4[1] + cl4[2] + cl4[3]) * (1.0f / (float)(MROWS * CBD)));
}

// -------------------------------------------------------------------- launch
extern "C" void kernel_launch(void* const* d_in, const int* in_sizes, int n_in,
                              void* d_out, int out_size, void* d_ws, size_t ws_size,
                              hipStream_t stream) {
    const float* x    = (const float*)d_in[0];
    const float* w_in = (const float*)d_in[1];
    const float* b_in = (const float*)d_in[2];
    const float* pos  = (const float*)d_in[3];
    const float* ln1g = (const float*)d_in[4];
    const float* ln1b = (const float*)d_in[5];
    const float* wq   = (const float*)d_in[6];
    const float* wk   = (const float*)d_in[7];
    const float* wv   = (const float*)d_in[8];
    const float* wo   = (const float*)d_in[9];
    const float* ln2g = (const float*)d_in[10];
    const float* ln2b = (const float*)d_in[11];
    const float* ffw1 = (const float*)d_in[12];
    const float* ffb1 = (const float*)d_in[13];
    const float* ffw2 = (const float*)d_in[14];
    const float* ffb2 = (const float*)d_in[15];
    const float* lnfg = (const float*)d_in[16];
    const float* lnfb = (const float*)d_in[17];
    const float* wout = (const float*)d_in[18];
    const float* bout = (const float*)d_in[19];
    const float* cb   = (const float*)d_in[20];
    float* out = (float*)d_out;

    const size_t MD  = (size_t)MROWS * DMODEL;   // 4,194,304
    const size_t MQ  = (size_t)MROWS * 1536;     // 12,582,912
    const size_t MF  = (size_t)MROWS * DFF;      // 16,777,216

    float* ws   = (float*)d_ws;
    float* h    = ws;
    float* t0   = h + MD;
    float* big  = t0 + MD;                   // MF floats (aliased region)
    float* zb   = big + MF;
    float* cbn  = zb + (size_t)MROWS * CBD;
    u16* cbh    = (u16*)(cbn + CBS);
    u16* cbl    = cbh + (size_t)CBS * CBD;
    u16* t0h    = (u16*)(cbh + 2 * (size_t)CBS * CBD);
    u16* t0l    = t0h + MD;
    u16* wb     = t0l + MD;

    // big aliases
    u16* qkvh = (u16*)big;
    u16* qkvl = qkvh + MQ;
    u16* obh  = qkvl + MQ;
    u16* obl  = obh + MD;
    u16* xh   = obh;
    u16* xl   = obl;
    u16* fmh  = (u16*)big;
    u16* fml  = fmh + MF;
    u16* zbh  = (u16*)big;        // VQ phase: big region is dead
    u16* zbl  = zbh + (size_t)MROWS * CBD;

    const size_t S_WIN  = (size_t)DMODEL * DMODEL;
    const size_t S_QKV  = (size_t)1536 * DMODEL * NDEPTH;
    const size_t S_WO   = S_WIN * NDEPTH;
    const size_t S_FF1  = (size_t)DFF * DMODEL * NDEPTH;
    const size_t S_FF2  = S_FF1;
    u16* winT_h = wb;
    u16* winT_l = winT_h + S_WIN;
    u16* qkvT_h = winT_l + S_WIN;
    u16* qkvT_l = qkvT_h + S_QKV;
    u16* woT_h  = qkvT_l + S_QKV;
    u16* woT_l  = woT_h + S_WO;
    u16* ff1T_h = woT_l + S_WO;
    u16* ff1T_l = ff1T_h + S_FF1;
    u16* ff2T_h = ff1T_l + S_FF1;
    u16* ff2T_l = ff2T_h + S_FF2;
    u16* VTh = ff2T_l + S_FF2;
    u16* VTl = VTh + (size_t)BATCH * SEQ * DMODEL;
    // split-K partial buffers (fp32, M x 512 each)
    float* spK0 = (float*)(VTl + (size_t)BATCH * SEQ * DMODEL);
    float* spK1 = spK0 + MD;

    dim3 blk(256);

    zero_kernel<<<dim3((out_size + 255) / 256), blk, 0, stream>>>(out, out_size);
    cbn_kernel<<<dim3(CBS / 256), blk, 0, stream>>>(cb, cbn);
    split_kernel<<<dim3((int)(CBS * CBD / 256)), blk, 0, stream>>>(cb, cbh, cbl, CBS * CBD);

    wtrans_kernel<<<dim3(16, 16, 1), blk, 0, stream>>>(w_in, winT_h, winT_l, DMODEL, DMODEL, 0, 0);
    wtrans_kernel<<<dim3(16, 16, NDEPTH), blk, 0, stream>>>(
        wq, qkvT_h, qkvT_l, DMODEL, DMODEL, (long)DMODEL * DMODEL, (long)1536 * DMODEL);
    wtrans_kernel<<<dim3(16, 16, NDEPTH), blk, 0, stream>>>(
        wk, qkvT_h + (size_t)512 * DMODEL, qkvT_l + (size_t)512 * DMODEL,
        DMODEL, DMODEL, (long)DMODEL * DMODEL, (long)1536 * DMODEL);
    wtrans_kernel<<<dim3(16, 16, NDEPTH), blk, 0, stream>>>(
        wv, qkvT_h + (size_t)1024 * DMODEL, qkvT_l + (size_t)1024 * DMODEL,
        DMODEL, DMODEL, (long)DMODEL * DMODEL, (long)1536 * DMODEL);
    wtrans_kernel<<<dim3(16, 16, NDEPTH), blk, 0, stream>>>(
        wo, woT_h, woT_l, DMODEL, DMODEL, (long)DMODEL * DMODEL, (long)DMODEL * DMODEL);
    wtrans_kernel<<<dim3(DFF / 32, 16, NDEPTH), blk, 0, stream>>>(
        ffw1, ff1T_h, ff1T_l, DMODEL, DFF, (long)DMODEL * DFF, (long)DFF * DMODEL);
    wtrans_kernel<<<dim3(16, DFF / 32, NDEPTH), blk, 0, stream>>>(
        ffw2, ff2T_h, ff2T_l, DFF, DMODEL, (long)DFF * DMODEL, (long)DMODEL * DFF);

    split_kernel<<<dim3((int)(MD / 256)), blk, 0, stream>>>(x, xh, xl, (int)MD);

    // input projection: split-K=2 -> spK0/spK1 (reduced+pos+bias inside ln1 of layer 0)
    gemm3_kernel<<<dim3(MROWS / 128, DMODEL / 128, 2), blk, 0, stream>>>(
        xh, xl, winT_h, winT_l, nullptr, nullptr, nullptr, nullptr, nullptr, nullptr,
        MROWS, DMODEL, DMODEL, 0, spK0, spK1, 256);

    for (int l = 0; l < NDEPTH; ++l) {
        // ln1 folds: l==0 -> input proj (+b_in+pos); l>0 -> previous ff2 (+ffb2[l-1])
        ln_kernel<<<dim3(MROWS / 4), blk, 0, stream>>>(
            (l == 0) ? nullptr : h, spK0, spK1,
            (l == 0) ? b_in : (ffb2 + (size_t)(l - 1) * DMODEL),
            (l == 0) ? pos : nullptr, h,
            nullptr, t0h, t0l, ln1g + l * DMODEL, ln1b + l * DMODEL);
        gemm3_kernel<<<dim3(MROWS / 128, 1536 / 128, 1), blk, 0, stream>>>(
            t0h, t0l, qkvT_h + (size_t)l * 1536 * DMODEL, qkvT_l + (size_t)l * 1536 * DMODEL,
            nullptr, qkvh, qkvl, nullptr, nullptr, nullptr, MROWS, 1536, DMODEL, 0,
            nullptr, nullptr, 0);
        vtrans_kernel<<<dim3(8, 8, 32), blk, 0, stream>>>(qkvh, qkvl, VTh, VTl);
        attn_mfma_kernel<<<dim3(BATCH * NHEADS * (SEQ / 16)), blk, 0, stream>>>(
            qkvh, qkvl, VTh, VTl, obh, obl);
        // wo: split-K=2 (reduced + residual inside ln2)
        gemm3_kernel<<<dim3(MROWS / 128, DMODEL / 128, 2), blk, 0, stream>>>(
            obh, obl, woT_h + (size_t)l * S_WIN, woT_l + (size_t)l * S_WIN,
            nullptr, nullptr, nullptr, nullptr, nullptr, nullptr,
            MROWS, DMODEL, DMODEL, 0, spK0, spK1, 256);
        ln_kernel<<<dim3(MROWS / 4), blk, 0, stream>>>(
            h, spK0, spK1, nullptr, nullptr, h,
            nullptr, t0h, t0l, ln2g + l * DMODEL, ln2b + l * DMODEL);
        gemm3_kernel<<<dim3(MROWS / 128, DFF / 128, 1), blk, 0, stream>>>(
            t0h, t0l, ff1T_h + (size_t)l * DFF * DMODEL, ff1T_l + (size_t)l * DFF * DMODEL,
            nullptr, fmh, fml, ffb1 + l * DFF, nullptr, nullptr, MROWS, DFF, DMODEL, 1,
            nullptr, nullptr, 0);
        // ff2: split-K=2 over K=2048 (reduced + ffb2 + residual in next ln1/lnf)
        gemm3_kernel<<<dim3(MROWS / 128, DMODEL / 128, 2), blk, 0, stream>>>(
            fmh, fml, ff2T_h + (size_t)l * DFF * DMODEL, ff2T_l + (size_t)l * DFF * DMODEL,
            nullptr, nullptr, nullptr, nullptr, nullptr, nullptr,
            MROWS, DMODEL, DFF, 0, spK0, spK1, 1024);
    }

    // final ln folds last ff2 (+ffb2[3]); writes fp32 t0 for the out-projection
    ln_kernel<<<dim3(MROWS / 4), blk, 0, stream>>>(
        h, spK0, spK1, ffb2 + (size_t)3 * DMODEL, nullptr, nullptr,
        t0, nullptr, nullptr, lnfg, lnfb);
    gemm_kernel<<<dim3(MROWS / 64, 1), blk, 0, stream>>>(t0, wout, zb, bout, MROWS, CBD, DMODEL);
    split_kernel<<<dim3((int)((size_t)MROWS * CBD / 256)), blk, 0, stream>>>(
        zb, zbh, zbl, MROWS * CBD);
    vq3_kernel<<<dim3(MROWS / 16), blk, 0, stream>>>(zb, zbh, zbl, cbh, cbl, cb, cbn, out);
}

// Round 6
// 1898.049 us; speedup vs baseline: 3.0094x; 1.1123x over previous
//
#include <hip/hip_runtime.h>
#include <cmath>

#define BATCH 16
#define SEQ 512
#define DMODEL 512
#define NDEPTH 4
#define NHEADS 8
#define DHEAD 64
#define DFF 2048
#define CBD 64
#define CBS 8192
#define MROWS (BATCH * SEQ) // 8192

typedef unsigned short u16;
typedef __attribute__((ext_vector_type(8))) short short8; // 8 bf16 = 4 VGPRs (MFMA A/B frag)
typedef __attribute__((ext_vector_type(4))) float f32x4;  // MFMA C/D frag
typedef __attribute__((ext_vector_type(4))) unsigned short u16x4;

// ---------------------------------------------------------------- bf16 helpers
__device__ __forceinline__ u16 f2bf(float f) {
    unsigned u = __float_as_uint(f);
    u += 0x7fff + ((u >> 16) & 1); // RNE
    return (u16)(u >> 16);
}
__device__ __forceinline__ float bf2f(u16 h) {
    return __uint_as_float(((unsigned)h) << 16);
}

// async global->LDS 16B: LDS dest must be wave-uniform base + lane*16
__device__ __forceinline__ void async16(u16* lds, const u16* g) {
    __builtin_amdgcn_global_load_lds(
        (const __attribute__((address_space(1))) unsigned int*)g,
        (__attribute__((address_space(3))) unsigned int*)lds, 16, 0, 0);
}

// gelu(u) = 0.5u(1+tanh(y)) = u*sigmoid(2y), 2y = 1.5957691216u + 0.0713548163u^3
// exp-form is mathematically identical; __expf -> v_exp_f32 (HW).
__device__ __forceinline__ float gelu_tanh(float u) {
    float t = fmaf(0.07135481627f * u, u * u, 1.5957691216f * u);
    return u / (1.0f + __expf(-t));
}

// ---------------------------------------------------------------- zero output
__global__ void zero_kernel(float* __restrict__ p, int n) {
    int i = blockIdx.x * 256 + threadIdx.x;
    if (i < n) p[i] = 0.0f;
}

// ------------------------------------------------------------- codebook norms
__global__ void cbn_kernel(const float* __restrict__ cb, float* __restrict__ cbn) {
    int c = blockIdx.x * 256 + threadIdx.x;
    if (c >= CBS) return;
    const float* row = cb + (size_t)c * CBD;
    float s = 0.0f;
#pragma unroll
    for (int d = 0; d < CBD; ++d) s += row[d] * row[d];
    cbn[c] = s;
}

// ------------------------- weight transpose + split: W [z][K][N] -> T [z][N][K]
__global__ __launch_bounds__(256) void wtrans_kernel(
    const float* __restrict__ W, u16* __restrict__ Th, u16* __restrict__ Tl,
    int K, int N, long inLS, long outLS) {
    __shared__ float t[32][33];
    const float* Ws = W + (size_t)blockIdx.z * inLS;
    u16* Tho = Th + (size_t)blockIdx.z * outLS;
    u16* Tlo = Tl + (size_t)blockIdx.z * outLS;
    int n0 = blockIdx.x * 32, k0 = blockIdx.y * 32;
    int tx = threadIdx.x & 31, ty = threadIdx.x >> 5;
#pragma unroll
    for (int r = ty; r < 32; r += 8) t[r][tx] = Ws[(size_t)(k0 + r) * N + n0 + tx];
    __syncthreads();
#pragma unroll
    for (int r = ty; r < 32; r += 8) {
        float v = t[tx][r];
        size_t o = (size_t)(n0 + r) * K + k0 + tx;
        u16 hh = f2bf(v);
        Tho[o] = hh;
        Tlo[o] = f2bf(v - bf2f(hh));
    }
}

// ------------------------ u16 transpose for V: qkv planes -> VT [b][512d][512s]
__global__ __launch_bounds__(256) void vtrans_kernel(
    const u16* __restrict__ Qh, const u16* __restrict__ Ql,
    u16* __restrict__ VTh, u16* __restrict__ VTl) {
    __shared__ u16 t[64][68];
    int s0 = blockIdx.x * 64, d0 = blockIdx.y * 64;
    int b = blockIdx.z & 15, plane = blockIdx.z >> 4;
    const u16* src = (plane ? Ql : Qh);
    u16* dst = (plane ? VTl : VTh);
    int tid = threadIdx.x;
    int rr = tid >> 4, c4 = (tid & 15) * 4;
#pragma unroll
    for (int i = 0; i < 4; ++i) {
        int r = rr + i * 16;
        const u16* p = src + (size_t)(b * SEQ + s0 + r) * 1536 + 1024 + d0 + c4;
        *(u16x4*)(&t[r][c4]) = *(const u16x4*)p;
    }
    __syncthreads();
#pragma unroll
    for (int i = 0; i < 4; ++i) {
        int r = rr + i * 16; // d-index within tile
        u16x4 v;
        v.x = t[c4 + 0][r]; v.y = t[c4 + 1][r]; v.z = t[c4 + 2][r]; v.w = t[c4 + 3][r];
        *(u16x4*)(dst + (size_t)b * SEQ * DMODEL + (size_t)(d0 + r) * SEQ + s0 + c4) = v;
    }
}

// ------------------------------------------------ elementwise fp32 -> (hi,lo)
__global__ void split_kernel(const float* __restrict__ X, u16* __restrict__ H,
                             u16* __restrict__ L, int n) {
    int i = blockIdx.x * 256 + threadIdx.x;
    if (i < n) {
        float v = X[i];
        u16 hh = f2bf(v);
        H[i] = hh;
        L[i] = f2bf(v - bf2f(hh));
    }
}

// ---------------------------------------- layernorm (+split-K reduce folding)
// x = X + C0 + C1 + bias2 + pos2 (any may be null); Xout=x; then LN -> Y/Yh/Yl
__global__ __launch_bounds__(256) void ln_kernel(
    const float* __restrict__ X,
    const float* __restrict__ C0, const float* __restrict__ C1,
    const float* __restrict__ bias2, const float* __restrict__ pos2,
    float* __restrict__ Xout,
    float* __restrict__ Y, u16* __restrict__ Yh, u16* __restrict__ Yl,
    const float* __restrict__ g, const float* __restrict__ b) {
    int row  = blockIdx.x * 4 + (threadIdx.x >> 6);
    int lane = threadIdx.x & 63;
    float v[8];
    float s = 0.0f;
#pragma unroll
    for (int j = 0; j < 8; ++j) {
        int d = lane + j * 64;
        size_t o = (size_t)row * DMODEL + d;
        float t = X ? X[o] : 0.0f;
        if (C0)    t += C0[o] + C1[o];
        if (bias2) t += bias2[d];
        if (pos2)  t += pos2[(size_t)(row & (SEQ - 1)) * DMODEL + d];
        v[j] = t;
        if (Xout) Xout[o] = t;
        s += t;
    }
#pragma unroll
    for (int off = 32; off; off >>= 1) s += __shfl_xor(s, off);
    float mu  = s * (1.0f / DMODEL);
    float var = 0.0f;
#pragma unroll
    for (int j = 0; j < 8; ++j) { float d = v[j] - mu; var += d * d; }
#pragma unroll
    for (int off = 32; off; off >>= 1) var += __shfl_xor(var, off);
    float r = rsqrtf(var * (1.0f / DMODEL) + 1e-5f);
#pragma unroll
    for (int j = 0; j < 8; ++j) {
        int d = lane + j * 64;
        float y = (v[j] - mu) * r * g[d] + b[d];
        size_t o = (size_t)row * DMODEL + d;
        if (Y) Y[o] = y;
        if (Yh) {
            u16 hh = f2bf(y);
            Yh[o] = hh;
            Yl[o] = f2bf(y - bf2f(hh));
        }
    }
}

// --------------------------------------------------------- bf16x3 MFMA GEMM
// Fused single K-loop: stages Ah,Al,Bh,Bl tiles together (32KB LDS) and issues
// all 3 split terms (48 MFMA) per barrier-pair: 3x fewer barriers, 2/3 staging
// bytes vs the 3-pass version. kslice>0: split-K partial -> Cs0/Cs1 (reduction
// folded into the following ln_kernel).
__global__ __launch_bounds__(256) void gemm3_kernel(
    const u16* __restrict__ Ah, const u16* __restrict__ Al,
    const u16* __restrict__ Bh, const u16* __restrict__ Bl,
    float* __restrict__ Cf, u16* __restrict__ Ch, u16* __restrict__ Cl,
    const float* __restrict__ bias, const float* __restrict__ res,
    const float* __restrict__ pos, int M, int N, int K, int gelu,
    float* __restrict__ Cs0, float* __restrict__ Cs1, int kslice) {
    __shared__ __align__(16) u16 AsH[128 * 32];
    __shared__ __align__(16) u16 AsL[128 * 32];
    __shared__ __align__(16) u16 BsH[128 * 32];
    __shared__ __align__(16) u16 BsL[128 * 32];

    int tid  = threadIdx.x;
    int w    = tid >> 6, lane = tid & 63;
    int wr   = w >> 1, wc = w & 1;
    int quad = lane >> 4, l16 = lane & 15;
    int m0   = blockIdx.x * 128;
    int n0   = blockIdx.y * 128;
    int ksA  = (kslice > 0) ? blockIdx.z * kslice : 0;
    int ksB  = (kslice > 0) ? ksA + kslice : K;

    f32x4 acc[4][4];
#pragma unroll
    for (int i = 0; i < 4; ++i)
#pragma unroll
        for (int j = 0; j < 4; ++j) acc[i][j] = (f32x4){0.f, 0.f, 0.f, 0.f};

    int off0 = tid * 16;
    int row0s = off0 >> 6, ke0 = (off0 & 63) >> 1;
    int off1 = 4096 + tid * 16;
    int row1s = off1 >> 6, ke1 = (off1 & 63) >> 1;

    const u16* AbaseH = Ah + (size_t)m0 * K;
    const u16* AbaseL = Al + (size_t)m0 * K;
    const u16* BbaseH = Bh + (size_t)n0 * K;
    const u16* BbaseL = Bl + (size_t)n0 * K;

    for (int ks = ksA; ks < ksB; ks += 32) {
        __syncthreads();
        async16(&AsH[off0 >> 1], AbaseH + (size_t)row0s * K + ks + ke0);
        async16(&AsH[off1 >> 1], AbaseH + (size_t)row1s * K + ks + ke1);
        async16(&AsL[off0 >> 1], AbaseL + (size_t)row0s * K + ks + ke0);
        async16(&AsL[off1 >> 1], AbaseL + (size_t)row1s * K + ks + ke1);
        async16(&BsH[off0 >> 1], BbaseH + (size_t)row0s * K + ks + ke0);
        async16(&BsH[off1 >> 1], BbaseH + (size_t)row1s * K + ks + ke1);
        async16(&BsL[off0 >> 1], BbaseL + (size_t)row0s * K + ks + ke0);
        async16(&BsL[off1 >> 1], BbaseL + (size_t)row1s * K + ks + ke1);
        __syncthreads();
        // persistent A frags (8 x short8), B frags loaded per-column
        short8 afh[4], afl[4];
#pragma unroll
        for (int i = 0; i < 4; ++i) {
            afh[i] = *(const short8*)&AsH[(wr * 64 + i * 16 + l16) * 32 + quad * 8];
            afl[i] = *(const short8*)&AsL[(wr * 64 + i * 16 + l16) * 32 + quad * 8];
        }
#pragma unroll
        for (int j = 0; j < 4; ++j) {
            short8 bh = *(const short8*)&BsH[(wc * 64 + j * 16 + l16) * 32 + quad * 8];
            short8 bl = *(const short8*)&BsL[(wc * 64 + j * 16 + l16) * 32 + quad * 8];
#pragma unroll
            for (int i = 0; i < 4; ++i) {
                acc[i][j] = __builtin_amdgcn_mfma_f32_16x16x32_bf16(afh[i], bh, acc[i][j], 0, 0, 0);
                acc[i][j] = __builtin_amdgcn_mfma_f32_16x16x32_bf16(afl[i], bh, acc[i][j], 0, 0, 0);
                acc[i][j] = __builtin_amdgcn_mfma_f32_16x16x32_bf16(afh[i], bl, acc[i][j], 0, 0, 0);
            }
        }
    }

    float* Cspl = (kslice > 0) ? (blockIdx.z ? Cs1 : Cs0) : nullptr;
    int mbase = m0 + wr * 64;
    int nbase = n0 + wc * 64;
#pragma unroll
    for (int mi = 0; mi < 4; ++mi)
#pragma unroll
        for (int ni = 0; ni < 4; ++ni) {
            f32x4 a = acc[mi][ni];
#pragma unroll
            for (int r = 0; r < 4; ++r) {
                int m = mbase + mi * 16 + quad * 4 + r;
                int n = nbase + ni * 16 + l16;
                float v = a[r];
                size_t o = (size_t)m * N + n;
                if (Cspl) { Cspl[o] = v; continue; }
                if (bias) v += bias[n];
                if (pos)  v += pos[(size_t)(m & (SEQ - 1)) * N + n];
                if (res)  v += res[(size_t)m * N + n];
                if (gelu) v = gelu_tanh(v);
                if (Cf) Cf[o] = v;
                if (Ch) {
                    u16 hh = f2bf(v);
                    Ch[o] = hh;
                    Cl[o] = f2bf(v - bf2f(hh));
                }
            }
        }
}

// ------------------------------------------------------------ fp32 GEMM (small)
__global__ __launch_bounds__(256) void gemm_kernel(
    const float* __restrict__ A, const float* __restrict__ Bm,
    float* __restrict__ C, const float* __restrict__ bias,
    int M, int N, int K) {
    __shared__ float As[16][68];
    __shared__ float Bs[16][64];
    int tid = threadIdx.x;
    int tx = tid & 15, ty = tid >> 4;
    int a_m = tid >> 2, a_k = (tid & 3) * 4;
    int b_k = tid >> 4, b_n = (tid & 15) * 4;
    const float* Arow = A + (size_t)(blockIdx.x * 64 + a_m) * K;
    const float* Bcol = Bm + (size_t)blockIdx.y * 64 + b_n;
    float acc[4][4] = {};
    for (int k0 = 0; k0 < K; k0 += 16) {
        float4 av = *(const float4*)(Arow + k0 + a_k);
        float4 bv = *(const float4*)(Bcol + (size_t)(k0 + b_k) * N);
        __syncthreads();
        As[a_k + 0][a_m] = av.x; As[a_k + 1][a_m] = av.y;
        As[a_k + 2][a_m] = av.z; As[a_k + 3][a_m] = av.w;
        *(float4*)(&Bs[b_k][b_n]) = bv;
        __syncthreads();
#pragma unroll
        for (int kk = 0; kk < 16; ++kk) {
            float4 a4 = *(const float4*)(&As[kk][ty * 4]);
            float4 b4 = *(const float4*)(&Bs[kk][tx * 4]);
            float ar[4] = {a4.x, a4.y, a4.z, a4.w};
            float br[4] = {b4.x, b4.y, b4.z, b4.w};
#pragma unroll
            for (int i = 0; i < 4; ++i)
#pragma unroll
                for (int j = 0; j < 4; ++j) acc[i][j] = fmaf(ar[i], br[j], acc[i][j]);
        }
    }
    int m0 = blockIdx.x * 64 + ty * 4;
    int n0 = blockIdx.y * 64 + tx * 4;
#pragma unroll
    for (int i = 0; i < 4; ++i) {
        float vv[4];
#pragma unroll
        for (int j = 0; j < 4; ++j) {
            float t = acc[i][j];
            if (bias) t += bias[n0 + j];
            vv[j] = t;
        }
        *(float4*)(C + (size_t)(m0 + i) * N + n0) = make_float4(vv[0], vv[1], vv[2], vv[3]);
    }
}

// ----------------------------------------------------------- MFMA attention
__global__ __launch_bounds__(256) void attn_mfma_kernel(
    const u16* __restrict__ QKh, const u16* __restrict__ QKl,
    const u16* __restrict__ VTh, const u16* __restrict__ VTl,
    u16* __restrict__ Oh, u16* __restrict__ Ol) {
    int qt = blockIdx.x & 31;
    int hh = (blockIdx.x >> 5) & 7;
    int bb = blockIdx.x >> 8;

    __shared__ __align__(16) unsigned char ldsbuf[16 * 544 * 2 * 2]; // 34816 B
    float* sc = (float*)ldsbuf;       // [16][512] fp32
    u16* Ph = (u16*)ldsbuf;           // [16][544]
    u16* Pl = Ph + 16 * 544;

    int tid = threadIdx.x;
    int w = tid >> 6, lane = tid & 63;
    int quad = lane >> 4, l16 = lane & 15;

    const u16* qrh = QKh + (size_t)(bb * SEQ + qt * 16 + l16) * 1536 + hh * 64 + quad * 8;
    const u16* qrl = QKl + (size_t)(bb * SEQ + qt * 16 + l16) * 1536 + hh * 64 + quad * 8;
    short8 Qh0 = *(const short8*)qrh;
    short8 Qh1 = *(const short8*)(qrh + 32);
    short8 Ql0 = *(const short8*)qrl;
    short8 Ql1 = *(const short8*)(qrl + 32);

    for (int kt = 0; kt < 8; ++kt) {
        int krow = bb * SEQ + kt * 64 + w * 16 + l16;
        const u16* krh = QKh + (size_t)krow * 1536 + 512 + hh * 64 + quad * 8;
        const u16* krl = QKl + (size_t)krow * 1536 + 512 + hh * 64 + quad * 8;
        short8 Kh0 = *(const short8*)krh;
        short8 Kh1 = *(const short8*)(krh + 32);
        short8 Kl0 = *(const short8*)krl;
        short8 Kl1 = *(const short8*)(krl + 32);
        f32x4 a = (f32x4){0.f, 0.f, 0.f, 0.f};
        a = __builtin_amdgcn_mfma_f32_16x16x32_bf16(Qh0, Kh0, a, 0, 0, 0);
        a = __builtin_amdgcn_mfma_f32_16x16x32_bf16(Qh1, Kh1, a, 0, 0, 0);
        a = __builtin_amdgcn_mfma_f32_16x16x32_bf16(Ql0, Kh0, a, 0, 0, 0);
        a = __builtin_amdgcn_mfma_f32_16x16x32_bf16(Ql1, Kh1, a, 0, 0, 0);
        a = __builtin_amdgcn_mfma_f32_16x16x32_bf16(Qh0, Kl0, a, 0, 0, 0);
        a = __builtin_amdgcn_mfma_f32_16x16x32_bf16(Qh1, Kl1, a, 0, 0, 0);
        int key = kt * 64 + w * 16 + l16;
#pragma unroll
        for (int r = 0; r < 4; ++r)
            sc[(quad * 4 + r) * 512 + key] = a[r] * 0.125f;
    }
    __syncthreads();

    float e[4][8];
#pragma unroll
    for (int rr = 0; rr < 4; ++rr) {
        int qi = w + rr * 4;
        float m = -1e30f;
#pragma unroll
        for (int j = 0; j < 8; ++j) { e[rr][j] = sc[qi * 512 + lane + j * 64]; m = fmaxf(m, e[rr][j]); }
#pragma unroll
        for (int off = 32; off; off >>= 1) m = fmaxf(m, __shfl_xor(m, off));
        float sum = 0.0f;
#pragma unroll
        for (int j = 0; j < 8; ++j) { e[rr][j] = __expf(e[rr][j] - m); sum += e[rr][j]; }
#pragma unroll
        for (int off = 32; off; off >>= 1) sum += __shfl_xor(sum, off);
        float inv = 1.0f / sum;
#pragma unroll
        for (int j = 0; j < 8; ++j) e[rr][j] *= inv;
    }
    __syncthreads();

#pragma unroll
    for (int rr = 0; rr < 4; ++rr) {
        int qi = w + rr * 4;
#pragma unroll
        for (int j = 0; j < 8; ++j) {
            float v = e[rr][j];
            u16 hv = f2bf(v);
            Ph[qi * 544 + lane + j * 64] = hv;
            Pl[qi * 544 + lane + j * 64] = f2bf(v - bf2f(hv));
        }
    }
    __syncthreads();

    const u16* vth = VTh + ((size_t)bb * SEQ + hh * 64 + w * 16 + l16) * SEQ + quad * 8;
    const u16* vtl = VTl + ((size_t)bb * SEQ + hh * 64 + w * 16 + l16) * SEQ + quad * 8;
    const u16* ph = Ph + l16 * 544 + quad * 8;
    const u16* pl = Pl + l16 * 544 + quad * 8;
    f32x4 acc0 = (f32x4){0.f, 0.f, 0.f, 0.f};
    f32x4 acc1 = (f32x4){0.f, 0.f, 0.f, 0.f};
#pragma unroll
    for (int ks = 0; ks < 512; ks += 64) {
        short8 P0h = *(const short8*)(ph + ks);
        short8 P0l = *(const short8*)(pl + ks);
        short8 V0h = *(const short8*)(vth + ks);
        short8 V0l = *(const short8*)(vtl + ks);
        short8 P1h = *(const short8*)(ph + ks + 32);
        short8 P1l = *(const short8*)(pl + ks + 32);
        short8 V1h = *(const short8*)(vth + ks + 32);
        short8 V1l = *(const short8*)(vtl + ks + 32);
        acc0 = __builtin_amdgcn_mfma_f32_16x16x32_bf16(P0h, V0h, acc0, 0, 0, 0);
        acc1 = __builtin_amdgcn_mfma_f32_16x16x32_bf16(P1h, V1h, acc1, 0, 0, 0);
        acc0 = __builtin_amdgcn_mfma_f32_16x16x32_bf16(P0l, V0h, acc0, 0, 0, 0);
        acc1 = __builtin_amdgcn_mfma_f32_16x16x32_bf16(P1l, V1h, acc1, 0, 0, 0);
        acc0 = __builtin_amdgcn_mfma_f32_16x16x32_bf16(P0h, V0l, acc0, 0, 0, 0);
        acc1 = __builtin_amdgcn_mfma_f32_16x16x32_bf16(P1h, V1l, acc1, 0, 0, 0);
    }
    f32x4 o = acc0 + acc1;
#pragma unroll
    for (int r = 0; r < 4; ++r) {
        int q = quad * 4 + r;
        size_t off = (size_t)(bb * SEQ + qt * 16 + q) * DMODEL + hh * 64 + w * 16 + l16;
        u16 hv = f2bf(o[r]);
        Oh[off] = hv;
        Ol[off] = f2bf(o[r] - bf2f(hv));
    }
}

// ----------------------------------------------------------------- MFMA VQ
__global__ __launch_bounds__(256) void vq3_kernel(
    const float* __restrict__ Z, const u16* __restrict__ Zh, const u16* __restrict__ Zl,
    const u16* __restrict__ CBh, const u16* __restrict__ CBl,
    const float* __restrict__ CB, const float* __restrict__ CBN,
    float* __restrict__ out) {
    __shared__ float sbest[4][16];
    __shared__ int sidx[4][16];
    __shared__ int ibest[16];
    __shared__ float psum[4][64];
    __shared__ float cl4[4];

    int tid = threadIdx.x;
    int w = tid >> 6, lane = tid & 63;
    int quad = lane >> 4, l16 = lane & 15;
    int row0 = blockIdx.x * 16;

    const u16* zph = Zh + (size_t)(row0 + l16) * CBD + quad * 8;
    const u16* zpl = Zl + (size_t)(row0 + l16) * CBD + quad * 8;
    short8 Z0h = *(const short8*)zph;
    short8 Z1h = *(const short8*)(zph + 32);
    short8 Z0l = *(const short8*)zpl;
    short8 Z1l = *(const short8*)(zpl + 32);

    float best[4] = {3.4e38f, 3.4e38f, 3.4e38f, 3.4e38f};
    int bidx[4] = {0, 0, 0, 0};

    int cbase = w * (CBS / 4);
#pragma unroll 2
    for (int t = 0; t < CBS / 4; t += 16) {
        int code = cbase + t + l16;
        const u16* cph = CBh + (size_t)code * CBD + quad * 8;
        const u16* cpl = CBl + (size_t)code * CBD + quad * 8;
        short8 C0h = *(const short8*)cph;
        short8 C1h = *(const short8*)(cph + 32);
        short8 C0l = *(const short8*)cpl;
        short8 C1l = *(const short8*)(cpl + 32);
        float cn = CBN[code];
        f32x4 a = (f32x4){0.f, 0.f, 0.f, 0.f};
        a = __builtin_amdgcn_mfma_f32_16x16x32_bf16(Z0h, C0h, a, 0, 0, 0);
        a = __builtin_amdgcn_mfma_f32_16x16x32_bf16(Z1h, C1h, a, 0, 0, 0);
        a = __builtin_amdgcn_mfma_f32_16x16x32_bf16(Z0l, C0h, a, 0, 0, 0);
        a = __builtin_amdgcn_mfma_f32_16x16x32_bf16(Z1l, C1h, a, 0, 0, 0);
        a = __builtin_amdgcn_mfma_f32_16x16x32_bf16(Z0h, C0l, a, 0, 0, 0);
        a = __builtin_amdgcn_mfma_f32_16x16x32_bf16(Z1h, C1l, a, 0, 0, 0);
#pragma unroll
        for (int r = 0; r < 4; ++r) {
            float s = cn - 2.0f * a[r];
            if (s < best[r]) { best[r] = s; bidx[r] = code; }
        }
    }
#pragma unroll
    for (int off = 8; off; off >>= 1) {
#pragma unroll
        for (int r = 0; r < 4; ++r) {
            float ov = __shfl_xor(best[r], off);
            int oi = __shfl_xor(bidx[r], off);
            if (ov < best[r] || (ov == best[r] && oi < bidx[r])) { best[r] = ov; bidx[r] = oi; }
        }
    }
    if (l16 == 0) {
#pragma unroll
        for (int r = 0; r < 4; ++r) {
            sbest[w][quad * 4 + r] = best[r];
            sidx[w][quad * 4 + r] = bidx[r];
        }
    }
    __syncthreads();
    if (tid < 16) {
        float bv = sbest[0][tid];
        int bi = sidx[0][tid];
#pragma unroll
        for (int ww = 1; ww < 4; ++ww) {
            float ov = sbest[ww][tid];
            int oi = sidx[ww][tid];
            if (ov < bv || (ov == bv && oi < bi)) { bv = ov; bi = oi; }
        }
        ibest[tid] = bi;
    }
    __syncthreads();

    int d2 = lane;
    float qacc = 0.0f, closs = 0.0f;
#pragma unroll
    for (int j = 0; j < 4; ++j) {
        int r2 = w * 4 + j;
        int bi = ibest[r2];
        float q = CB[(size_t)bi * CBD + d2];
        float z = Z[(size_t)(row0 + r2) * CBD + d2];
        qacc += q;
        float df = q - z;
        closs += df * df;
    }
    psum[w][d2] = qacc;
#pragma unroll
    for (int off = 32; off; off >>= 1) closs += __shfl_xor(closs, off);
    if (d2 == 0) cl4[w] = closs;
    __syncthreads();
    if (tid < 64) {
        float t = psum[0][tid] + psum[1][tid] + psum[2][tid] + psum[3][tid];
        int b = row0 >> 9;
        atomicAdd(out + b * 64 + tid, t);
    }
    if (tid == 0)
        atomicAdd(out + 1024, (cl4[0] + cl4[1] + cl4[2] + cl4[3]) * (1.0f / (float)(MROWS * CBD)));
}

// -------------------------------------------------------------------- launch
extern "C" void kernel_launch(void* const* d_in, const int* in_sizes, int n_in,
                              void* d_out, int out_size, void* d_ws, size_t ws_size,
                              hipStream_t stream) {
    const float* x    = (const float*)d_in[0];
    const float* w_in = (const float*)d_in[1];
    const float* b_in = (const float*)d_in[2];
    const float* pos  = (const float*)d_in[3];
    const float* ln1g = (const float*)d_in[4];
    const float* ln1b = (const float*)d_in[5];
    const float* wq   = (const float*)d_in[6];
    const float* wk   = (const float*)d_in[7];
    const float* wv   = (const float*)d_in[8];
    const float* wo   = (const float*)d_in[9];
    const float* ln2g = (const float*)d_in[10];
    const float* ln2b = (const float*)d_in[11];
    const float* ffw1 = (const float*)d_in[12];
    const float* ffb1 = (const float*)d_in[13];
    const float* ffw2 = (const float*)d_in[14];
    const float* ffb2 = (const float*)d_in[15];
    const float* lnfg = (const float*)d_in[16];
    const float* lnfb = (const float*)d_in[17];
    const float* wout = (const float*)d_in[18];
    const float* bout = (const float*)d_in[19];
    const float* cb   = (const float*)d_in[20];
    float* out = (float*)d_out;

    const size_t MD  = (size_t)MROWS * DMODEL;   // 4,194,304
    const size_t MQ  = (size_t)MROWS * 1536;     // 12,582,912
    const size_t MF  = (size_t)MROWS * DFF;      // 16,777,216

    float* ws   = (float*)d_ws;
    float* h    = ws;
    float* t0   = h + MD;
    float* big  = t0 + MD;                   // MF floats (aliased region)
    float* zb   = big + MF;
    float* cbn  = zb + (size_t)MROWS * CBD;
    u16* cbh    = (u16*)(cbn + CBS);
    u16* cbl    = cbh + (size_t)CBS * CBD;
    u16* t0h    = (u16*)(cbh + 2 * (size_t)CBS * CBD);
    u16* t0l    = t0h + MD;
    u16* wb     = t0l + MD;

    // big aliases
    u16* qkvh = (u16*)big;
    u16* qkvl = qkvh + MQ;
    u16* obh  = qkvl + MQ;
    u16* obl  = obh + MD;
    u16* xh   = obh;
    u16* xl   = obl;
    u16* fmh  = (u16*)big;
    u16* fml  = fmh + MF;
    u16* zbh  = (u16*)big;        // VQ phase: big region is dead
    u16* zbl  = zbh + (size_t)MROWS * CBD;

    const size_t S_WIN  = (size_t)DMODEL * DMODEL;
    const size_t S_QKV  = (size_t)1536 * DMODEL * NDEPTH;
    const size_t S_WO   = S_WIN * NDEPTH;
    const size_t S_FF1  = (size_t)DFF * DMODEL * NDEPTH;
    const size_t S_FF2  = S_FF1;
    u16* winT_h = wb;
    u16* winT_l = winT_h + S_WIN;
    u16* qkvT_h = winT_l + S_WIN;
    u16* qkvT_l = qkvT_h + S_QKV;
    u16* woT_h  = qkvT_l + S_QKV;
    u16* woT_l  = woT_h + S_WO;
    u16* ff1T_h = woT_l + S_WO;
    u16* ff1T_l = ff1T_h + S_FF1;
    u16* ff2T_h = ff1T_l + S_FF1;
    u16* ff2T_l = ff2T_h + S_FF2;
    u16* VTh = ff2T_l + S_FF2;
    u16* VTl = VTh + (size_t)BATCH * SEQ * DMODEL;
    // split-K partial buffers (fp32, M x 512 each)
    float* spK0 = (float*)(VTl + (size_t)BATCH * SEQ * DMODEL);
    float* spK1 = spK0 + MD;

    dim3 blk(256);

    zero_kernel<<<dim3((out_size + 255) / 256), blk, 0, stream>>>(out, out_size);
    cbn_kernel<<<dim3(CBS / 256), blk, 0, stream>>>(cb, cbn);
    split_kernel<<<dim3((int)(CBS * CBD / 256)), blk, 0, stream>>>(cb, cbh, cbl, CBS * CBD);

    wtrans_kernel<<<dim3(16, 16, 1), blk, 0, stream>>>(w_in, winT_h, winT_l, DMODEL, DMODEL, 0, 0);
    wtrans_kernel<<<dim3(16, 16, NDEPTH), blk, 0, stream>>>(
        wq, qkvT_h, qkvT_l, DMODEL, DMODEL, (long)DMODEL * DMODEL, (long)1536 * DMODEL);
    wtrans_kernel<<<dim3(16, 16, NDEPTH), blk, 0, stream>>>(
        wk, qkvT_h + (size_t)512 * DMODEL, qkvT_l + (size_t)512 * DMODEL,
        DMODEL, DMODEL, (long)DMODEL * DMODEL, (long)1536 * DMODEL);
    wtrans_kernel<<<dim3(16, 16, NDEPTH), blk, 0, stream>>>(
        wv, qkvT_h + (size_t)1024 * DMODEL, qkvT_l + (size_t)1024 * DMODEL,
        DMODEL, DMODEL, (long)DMODEL * DMODEL, (long)1536 * DMODEL);
    wtrans_kernel<<<dim3(16, 16, NDEPTH), blk, 0, stream>>>(
        wo, woT_h, woT_l, DMODEL, DMODEL, (long)DMODEL * DMODEL, (long)DMODEL * DMODEL);
    wtrans_kernel<<<dim3(DFF / 32, 16, NDEPTH), blk, 0, stream>>>(
        ffw1, ff1T_h, ff1T_l, DMODEL, DFF, (long)DMODEL * DFF, (long)DFF * DMODEL);
    wtrans_kernel<<<dim3(16, DFF / 32, NDEPTH), blk, 0, stream>>>(
        ffw2, ff2T_h, ff2T_l, DFF, DMODEL, (long)DFF * DMODEL, (long)DMODEL * DFF);

    split_kernel<<<dim3((int)(MD / 256)), blk, 0, stream>>>(x, xh, xl, (int)MD);

    // input projection: split-K=2 -> spK0/spK1 (reduced+pos+bias inside ln1 of layer 0)
    gemm3_kernel<<<dim3(MROWS / 128, DMODEL / 128, 2), blk, 0, stream>>>(
        xh, xl, winT_h, winT_l, nullptr, nullptr, nullptr, nullptr, nullptr, nullptr,
        MROWS, DMODEL, DMODEL, 0, spK0, spK1, 256);

    for (int l = 0; l < NDEPTH; ++l) {
        // ln1 folds: l==0 -> input proj (+b_in+pos); l>0 -> previous ff2 (+ffb2[l-1])
        ln_kernel<<<dim3(MROWS / 4), blk, 0, stream>>>(
            (l == 0) ? nullptr : h, spK0, spK1,
            (l == 0) ? b_in : (ffb2 + (size_t)(l - 1) * DMODEL),
            (l == 0) ? pos : nullptr, h,
            nullptr, t0h, t0l, ln1g + l * DMODEL, ln1b + l * DMODEL);
        gemm3_kernel<<<dim3(MROWS / 128, 1536 / 128, 1), blk, 0, stream>>>(
            t0h, t0l, qkvT_h + (size_t)l * 1536 * DMODEL, qkvT_l + (size_t)l * 1536 * DMODEL,
            nullptr, qkvh, qkvl, nullptr, nullptr, nullptr, MROWS, 1536, DMODEL, 0,
            nullptr, nullptr, 0);
        vtrans_kernel<<<dim3(8, 8, 32), blk, 0, stream>>>(qkvh, qkvl, VTh, VTl);
        attn_mfma_kernel<<<dim3(BATCH * NHEADS * (SEQ / 16)), blk, 0, stream>>>(
            qkvh, qkvl, VTh, VTl, obh, obl);
        // wo: split-K=2 (reduced + residual inside ln2)
        gemm3_kernel<<<dim3(MROWS / 128, DMODEL / 128, 2), blk, 0, stream>>>(
            obh, obl, woT_h + (size_t)l * S_WIN, woT_l + (size_t)l * S_WIN,
            nullptr, nullptr, nullptr, nullptr, nullptr, nullptr,
            MROWS, DMODEL, DMODEL, 0, spK0, spK1, 256);
        ln_kernel<<<dim3(MROWS / 4), blk, 0, stream>>>(
            h, spK0, spK1, nullptr, nullptr, h,
            nullptr, t0h, t0l, ln2g + l * DMODEL, ln2b + l * DMODEL);
        gemm3_kernel<<<dim3(MROWS / 128, DFF / 128, 1), blk, 0, stream>>>(
            t0h, t0l, ff1T_h + (size_t)l * DFF * DMODEL, ff1T_l + (size_t)l * DFF * DMODEL,
            nullptr, fmh, fml, ffb1 + l * DFF, nullptr, nullptr, MROWS, DFF, DMODEL, 1,
            nullptr, nullptr, 0);
        // ff2: split-K=2 over K=2048 (reduced + ffb2 + residual in next ln1/lnf)
        gemm3_kernel<<<dim3(MROWS / 128, DMODEL / 128, 2), blk, 0, stream>>>(
            fmh, fml, ff2T_h + (size_t)l * DFF * DMODEL, ff2T_l + (size_t)l * DFF * DMODEL,
            nullptr, nullptr, nullptr, nullptr, nullptr, nullptr,
            MROWS, DMODEL, DFF, 0, spK0, spK1, 1024);
    }

    // final ln folds last ff2 (+ffb2[3]); writes fp32 t0 for the out-projection
    ln_kernel<<<dim3(MROWS / 4), blk, 0, stream>>>(
        h, spK0, spK1, ffb2 + (size_t)3 * DMODEL, nullptr, nullptr,
        t0, nullptr, nullptr, lnfg, lnfb);
    gemm_kernel<<<dim3(MROWS / 64, 1), blk, 0, stream>>>(t0, wout, zb, bout, MROWS, CBD, DMODEL);
    split_kernel<<<dim3((int)((size_t)MROWS * CBD / 256)), blk, 0, stream>>>(
        zb, zbh, zbl, MROWS * CBD);
    vq3_kernel<<<dim3(MROWS / 16), blk, 0, stream>>>(zb, zbh, zbl, cbh, cbl, cb, cbn, out);
}